// Round 12
// baseline (486.265 us; speedup 1.0000x reference)
//
#include <hip/hip_runtime.h>
#include <hip/hip_bf16.h>
#include <stdint.h>
#include <math.h>

// Problem constants
#define B_  32
#define N_  512
#define G_  512
#define D_  512
#define H_  16
#define KD_ 32

using bf16x8 = __attribute__((ext_vector_type(8))) short;
using f32x4  = __attribute__((ext_vector_type(4))) float;
typedef unsigned short u16;

__device__ __forceinline__ u16 f2b(float x) {
  union { __hip_bfloat16 h; u16 u; } c;
  c.h = __float2bfloat16(x);
  return c.u;
}
__device__ __forceinline__ float b2f(u16 u) {
  union { float f; unsigned int i; } c;
  c.i = ((unsigned int)u) << 16;
  return c.f;
}

// async global->LDS, 16B per lane. LDS dest is wave-uniform base; HW adds lane*16.
__device__ __forceinline__ void async16(void* lds, const void* g) {
  __builtin_amdgcn_global_load_lds(
      (const __attribute__((address_space(1))) unsigned int*)(uintptr_t)g,
      (__attribute__((address_space(3))) unsigned int*)(uintptr_t)lds,
      16, 0, 0);
}

// ---------------------------------------------------------------------------
// mean partials fused with hi/lo split of encoded_nodes. grid (32,8), block 512.
__global__ __launch_bounds__(512) void mean_split_kernel(
    const float* __restrict__ enc, u16* __restrict__ hi, u16* __restrict__ lo,
    float* __restrict__ partial)
{
  const int b  = blockIdx.x;
  const int nc = blockIdx.y;       // 8 chunks of 64 n
  const int d  = threadIdx.x;      // 512
  const size_t base = ((size_t)b * N_ + (size_t)nc * 64) * D_ + d;
  float psum = 0.f;
  for (int i = 0; i < 64; ++i) {
    float v = enc[base + (size_t)i * D_];
    psum += v;
    u16 h = f2b(v);
    hi[base + (size_t)i * D_] = h;
    lo[base + (size_t)i * D_] = f2b(v - b2f(h));
  }
  partial[((size_t)b * 8 + nc) * D_ + d] = psum;
}

// graph mean + qg fused: qg[b][d] = dot(mean_n enc[b], Wq_graph[d]). grid 32, block 512.
__global__ __launch_bounds__(512) void meanqg_kernel(
    const float* __restrict__ partial, const float* __restrict__ Wq,
    float* __restrict__ qg)
{
  __shared__ float gl[512];
  const int b = blockIdx.x, d = threadIdx.x;
  float s = 0.f;
  for (int c = 0; c < 8; ++c) s += partial[((size_t)b * 8 + c) * D_ + d];
  gl[d] = s * (1.0f / N_);
  __syncthreads();
  const float* w = Wq + (size_t)d * D_;
  float q = 0.f;
  for (int k = 0; k < D_; ++k) q += gl[k] * w[k];
  qg[b * D_ + d] = q;
}

// generic fp32 -> (hi,lo) bf16 split, 4 elems/thread
__global__ void split4_kernel(const float* __restrict__ in,
                              u16* __restrict__ hi, u16* __restrict__ lo, int n4)
{
  int i = blockIdx.x * blockDim.x + threadIdx.x;
  if (i < n4) {
    float4 v = ((const float4*)in)[i];
    ushort4 h, l;
    h.x = f2b(v.x); l.x = f2b(v.x - b2f(h.x));
    h.y = f2b(v.y); l.y = f2b(v.y - b2f(h.y));
    h.z = f2b(v.z); l.z = f2b(v.z - b2f(h.z));
    h.w = f2b(v.w); l.w = f2b(v.w - b2f(h.w));
    ((ushort4*)hi)[i] = h;
    ((ushort4*)lo)[i] = l;
  }
}

// all weight splits in one launch. grid (256, 4), block 256.
__global__ __launch_bounds__(256) void wsplit_all_kernel(
    const float* __restrict__ Wqf, const float* __restrict__ Wqla,
    const float* __restrict__ Wk,  const float* __restrict__ Wv,
    const float* __restrict__ Wc,
    u16* __restrict__ Wqlhi, u16* __restrict__ Wqllo,
    u16* __restrict__ Wkvhi, u16* __restrict__ Wkvlo,
    u16* __restrict__ Wchi,  u16* __restrict__ Wclo)
{
  const int i = blockIdx.x * 256 + threadIdx.x;   // float4 index < 65536
  const int which = blockIdx.y;
  float4 v;
  u16 *hi, *lo;
  if (which == 0) {
    float4 a = ((const float4*)Wqf)[i];
    float4 b = ((const float4*)Wqla)[i];
    v = make_float4(a.x + b.x, a.y + b.y, a.z + b.z, a.w + b.w);
    hi = Wqlhi; lo = Wqllo;
  } else if (which == 1) {
    v = ((const float4*)Wk)[i]; hi = Wkvhi; lo = Wkvlo;
  } else if (which == 2) {
    v = ((const float4*)Wv)[i]; hi = Wkvhi + 262144; lo = Wkvlo + 262144;
  } else {
    v = ((const float4*)Wc)[i]; hi = Wchi; lo = Wclo;
  }
  ushort4 h, l;
  h.x = f2b(v.x); l.x = f2b(v.x - b2f(h.x));
  h.y = f2b(v.y); l.y = f2b(v.y - b2f(h.y));
  h.z = f2b(v.z); l.z = f2b(v.z - b2f(h.z));
  h.w = f2b(v.w); l.w = f2b(v.w - b2f(h.w));
  ((ushort4*)hi)[i] = h;
  ((ushort4*)lo)[i] = l;
}

// ---------------------------------------------------------------------------
// rowmax of mask per (b,g) row. grid 4096, block 256 (4 rows/block, 1 wave/row).
__global__ __launch_bounds__(256) void rowmax_kernel(
    const float* __restrict__ mask, float* __restrict__ rmx)
{
  const int row  = blockIdx.x * 4 + (threadIdx.x >> 6);
  const int lane = threadIdx.x & 63;
  const float* r = mask + (size_t)row * N_;
  float4 a  = *(const float4*)&r[lane * 8];
  float4 b4 = *(const float4*)&r[lane * 8 + 4];
  float m = fmaxf(fmaxf(fmaxf(a.x, a.y), fmaxf(a.z, a.w)),
                  fmaxf(fmaxf(b4.x, b4.y), fmaxf(b4.z, b4.w)));
#pragma unroll
  for (int w = 1; w < 64; w <<= 1) m = fmaxf(m, __shfl_xor(m, w));
  if (lane == 0) rmx[row] = m;
}

// max_n ||k_n||_2 per (b,h), from khi [16384][512]. grid 512, block 64 (1 wave).
__global__ __launch_bounds__(64) void kmax_kernel(
    const u16* __restrict__ khi, float* __restrict__ kmx)
{
  const int b = blockIdx.x >> 4, h = blockIdx.x & 15;
  const int lane = threadIdx.x;
  float mx = 0.f;
  for (int i = 0; i < 8; ++i) {
    const int n = i * 64 + lane;
    const unsigned int* p =
        (const unsigned int*)&khi[((size_t)b * 512 + n) * 512 + h * 32];
    float s = 0.f;
#pragma unroll
    for (int w = 0; w < 16; ++w) {
      unsigned int u = p[w];
      float f0 = __uint_as_float(u << 16);
      float f1 = __uint_as_float(u & 0xffff0000u);
      s = fmaf(f0, f0, s);
      s = fmaf(f1, f1, s);
    }
    mx = fmaxf(mx, s);
  }
#pragma unroll
  for (int w = 1; w < 64; w <<= 1) mx = fmaxf(mx, __shfl_xor(mx, w));
  if (lane == 0) kmx[blockIdx.x] = sqrtf(mx) * 1.01f;  // covers dropped lo parts
}

// ---------------------------------------------------------------------------
// C[M,N] = A[M,K] @ B[N,K]^T with split-precision bf16 (hi+lo pairs), fp32 accum.
// acc += Alo*Bhi + Ahi*Blo + Ahi*Bhi   (lo*lo dropped, ~2^-18)
// OUTMODE: 1 = hi/lo bf16 row-major,
//          3 = kv fused: c<512 -> K row-major; c>=512 -> VT[b][h][d][n] scatter
// BIASMODE: 0 none, 1 +bias[(r>>9)*512 + c] (qg broadcast), 2 +bias[c] (bcomb)
// 128x128 tile, BK=32, 4 waves (2x2). 1D grid nb, nb%8==0. XCD-chunked x-major
// swizzle: each XCD owns contiguous logical ids with constant B-panel (bx).
template<int OUTMODE, int BIASMODE>
__global__ __launch_bounds__(256) void gemm_split_kernel(
    const u16* __restrict__ Ahi, const u16* __restrict__ Alo,
    const u16* __restrict__ Bhi, const u16* __restrict__ Blo,
    void* __restrict__ Chi, void* __restrict__ Clo,
    void* __restrict__ Dhi, void* __restrict__ Dlo,
    const float* __restrict__ bias,
    int M, int N, int K, int gy)
{
  __shared__ __align__(16) u16 AhS[4096], AlS[4096], BhS[4096], BlS[4096];

  const int nb8     = gridDim.x >> 3;
  const int logical = (blockIdx.x & 7) * nb8 + (blockIdx.x >> 3);
  const int bx = logical / gy;
  const int by = logical - bx * gy;
  const int brow = by * 128;
  const int bcol = bx * 128;

  const int tid  = threadIdx.x;
  const int wid  = tid >> 6;
  const int lane = tid & 63;
  const int wr = wid >> 1, wc = wid & 1;

  f32x4 acc[4][4] = {};

  const int c0   = wid * 2;
  const int srow = lane >> 2;        // 0..15
  const int skk  = (lane & 3) * 8;   // 0,8,16,24

  const size_t g0 = (size_t)(brow + c0 * 16      + srow) * K + skk;
  const size_t g1 = (size_t)(brow + c0 * 16 + 16 + srow) * K + skk;
  const size_t h0 = (size_t)(bcol + c0 * 16      + srow) * K + skk;
  const size_t h1 = (size_t)(bcol + c0 * 16 + 16 + srow) * K + skk;
  u16* lA0 = &AhS[c0 * 512]; u16* lA1 = &AhS[c0 * 512 + 512];
  u16* la0 = &AlS[c0 * 512]; u16* la1 = &AlS[c0 * 512 + 512];
  u16* lB0 = &BhS[c0 * 512]; u16* lB1 = &BhS[c0 * 512 + 512];
  u16* lb0 = &BlS[c0 * 512]; u16* lb1 = &BlS[c0 * 512 + 512];

  const int aoff = (wr * 64 + (lane & 15)) * 32 + (lane >> 4) * 8;
  const int boff = (wc * 64 + (lane & 15)) * 32 + (lane >> 4) * 8;

  for (int k0 = 0; k0 < K; k0 += 32) {
    async16(lA0, Ahi + g0 + k0);
    async16(lA1, Ahi + g1 + k0);
    async16(la0, Alo + g0 + k0);
    async16(la1, Alo + g1 + k0);
    async16(lB0, Bhi + h0 + k0);
    async16(lB1, Bhi + h1 + k0);
    async16(lb0, Blo + h0 + k0);
    async16(lb1, Blo + h1 + k0);
    __syncthreads();   // drains vmcnt(0) before barrier

    bf16x8 ah[4], al[4], bh[4], bl[4];
#pragma unroll
    for (int m = 0; m < 4; ++m) {
      ah[m] = *(const bf16x8*)&AhS[aoff + m * 512];
      al[m] = *(const bf16x8*)&AlS[aoff + m * 512];
    }
#pragma unroll
    for (int n = 0; n < 4; ++n) {
      bh[n] = *(const bf16x8*)&BhS[boff + n * 512];
      bl[n] = *(const bf16x8*)&BlS[boff + n * 512];
    }
#pragma unroll
    for (int m = 0; m < 4; ++m)
#pragma unroll
      for (int n = 0; n < 4; ++n) {
        f32x4 t = acc[m][n];
        t = __builtin_amdgcn_mfma_f32_16x16x32_bf16(al[m], bh[n], t, 0, 0, 0);
        t = __builtin_amdgcn_mfma_f32_16x16x32_bf16(ah[m], bl[n], t, 0, 0, 0);
        t = __builtin_amdgcn_mfma_f32_16x16x32_bf16(ah[m], bh[n], t, 0, 0, 0);
        acc[m][n] = t;
      }
    __syncthreads();   // protect LDS before next stage overwrites
  }

  // epilogue. C/D layout: col = lane&15, row = (lane>>4)*4 + reg
  const int r0 = brow + wr * 64 + (lane >> 4) * 4;
  const int cbase = bcol + wc * 64 + (lane & 15);
#pragma unroll
  for (int m = 0; m < 4; ++m) {
#pragma unroll
    for (int n = 0; n < 4; ++n) {
      const int c = cbase + n * 16;
#pragma unroll
      for (int j = 0; j < 4; ++j) {
        const int r = r0 + m * 16 + j;
        float v = acc[m][n][j];
        if (BIASMODE == 1) v += bias[(r >> 9) * 512 + c];
        if (BIASMODE == 2) v += bias[c];
        u16 hv = f2b(v);
        u16 lv = f2b(v - b2f(hv));
        if (OUTMODE == 1) {
          ((u16*)Chi)[(size_t)r * N + c] = hv;
          ((u16*)Clo)[(size_t)r * N + c] = lv;
        } else {  // OUTMODE == 3
          if (c < 512) {
            ((u16*)Chi)[(size_t)r * 512 + c] = hv;
            ((u16*)Clo)[(size_t)r * 512 + c] = lv;
          } else {
            const int bb = r >> 9, nn = r & 511, hh = (c >> 5) & 15, dd = c & 31;
            const size_t idx = (((size_t)bb * 16 + hh) * 32 + dd) * 512 + nn;
            ((u16*)Dhi)[idx] = hv;
            ((u16*)Dlo)[idx] = lv;
          }
        }
      }
    }
  }
}

// ---------------------------------------------------------------------------
// Stage-1 attention — round-9 attn_mfma6 VERBATIM (known-good: 162us, absmax
// 1.525879e-05). Single pass with analytic shift m_hat >= row max (exact after
// normalization). P hi/lo via v_cvt_pk_bf16_f32; row sums via P@ones MFMA;
// per-wave P LDS (no barriers); O in-place over Q. grid 2048, block 256.
// DO NOT reschedule this kernel (unroll pragmas / hoisted pointer arrays /
// launch_bounds min-waves): two independent attempts (r7, r11) degraded absmax
// 1.5e-5 -> 6-9e-5.
__global__ __launch_bounds__(256) void attn_mfma6_kernel(
    u16* __restrict__ Qhi, u16* __restrict__ Qlo,               // in: Q, out: O
    const u16* __restrict__ Khi, const u16* __restrict__ Klo,   // [16384][512]
    const u16* __restrict__ VThi, const u16* __restrict__ VTlo, // [b][h][32][512]
    const float* __restrict__ mask,
    const float* __restrict__ rowmaxb,   // [16384]
    const float* __restrict__ kmaxb)     // [512]
{
  __shared__ __align__(16) u16 Ph[4][32][56], Pl[4][32][56];  // 112B row stride

  const int tid = threadIdx.x, wid = tid >> 6, lane = tid & 63;
  const int id   = blockIdx.x;
  const int h    = id & 15;
  const int gblk = (id >> 4) & 3;
  const int b    = id >> 6;
  const int g0   = gblk * 128 + wid * 32;
  const int colq = lane & 15, rowg = lane >> 4;

  const size_t qb = ((size_t)b * G_ + g0) * D_ + h * KD_;
  const size_t kb = ((size_t)b * N_) * D_ + h * KD_;
  const size_t vb = (((size_t)b * H_ + h) * KD_) * (size_t)N_;
  const float* Mb = mask + ((size_t)b * G_ + g0) * N_;

  bf16x8 qh[2], ql[2];
  qh[0] = *(const bf16x8*)&Qhi[qb + (size_t)colq * D_ + rowg * 8];
  ql[0] = *(const bf16x8*)&Qlo[qb + (size_t)colq * D_ + rowg * 8];
  qh[1] = *(const bf16x8*)&Qhi[qb + (size_t)(16 + colq) * D_ + rowg * 8];
  ql[1] = *(const bf16x8*)&Qlo[qb + (size_t)(16 + colq) * D_ + rowg * 8];

  const float scale = 0.17677669529663687f;  // 1/sqrt(32)
  const f32x4 zf = {0.f, 0.f, 0.f, 0.f};
  const bf16x8 ones = {0x3F80, 0x3F80, 0x3F80, 0x3F80, 0x3F80, 0x3F80, 0x3F80, 0x3F80};

  // ---- prologue: per-row shift m_hat (upper bound of row max) ----
  const float km = kmaxb[b * 16 + h];
  float nq2[2];
#pragma unroll
  for (int rf = 0; rf < 2; ++rf) {
    float s = 0.f;
    const unsigned int* qw = (const unsigned int*)&qh[rf];
#pragma unroll
    for (int w = 0; w < 4; ++w) {
      unsigned int u = qw[w];
      float f0 = __uint_as_float(u << 16);
      float f1 = __uint_as_float(u & 0xffff0000u);
      s = fmaf(f0, f0, s);
      s = fmaf(f1, f1, s);
    }
    s += __shfl_xor(s, 16);
    s += __shfl_xor(s, 32);
    nq2[rf] = s;
  }
  float mrow[2][4];
#pragma unroll
  for (int rf = 0; rf < 2; ++rf)
#pragma unroll
    for (int j = 0; j < 4; ++j) {
      const int r16 = rowg * 4 + j;
      float nq = sqrtf(__shfl(nq2[rf], r16)) * 1.01f;
      mrow[rf][j] = scale * nq * km + rowmaxb[(size_t)b * G_ + g0 + rf * 16 + r16];
    }

  // ---- single pass: P = exp(s - m_hat), P.V and P.1 accumulation ----
  f32x4 o[2][2] = {};
  f32x4 os[2] = {};

  for (int n0 = 0; n0 < N_; n0 += 32) {
    bf16x8 kh0 = *(const bf16x8*)&Khi[kb + (size_t)(n0 + colq) * D_ + rowg * 8];
    bf16x8 kl0 = *(const bf16x8*)&Klo[kb + (size_t)(n0 + colq) * D_ + rowg * 8];
    bf16x8 kh1 = *(const bf16x8*)&Khi[kb + (size_t)(n0 + 16 + colq) * D_ + rowg * 8];
    bf16x8 kl1 = *(const bf16x8*)&Klo[kb + (size_t)(n0 + 16 + colq) * D_ + rowg * 8];
    // V loads issued early: latency hides under QK^T + softmax VALU work
    bf16x8 vh0 = *(const bf16x8*)&VThi[vb + (size_t)colq * N_ + n0 + rowg * 8];
    bf16x8 vl0 = *(const bf16x8*)&VTlo[vb + (size_t)colq * N_ + n0 + rowg * 8];
    bf16x8 vh1 = *(const bf16x8*)&VThi[vb + (size_t)(16 + colq) * N_ + n0 + rowg * 8];
    bf16x8 vl1 = *(const bf16x8*)&VTlo[vb + (size_t)(16 + colq) * N_ + n0 + rowg * 8];

#pragma unroll
    for (int rf = 0; rf < 2; ++rf) {
      f32x4 t0 = __builtin_amdgcn_mfma_f32_16x16x32_bf16(ql[rf], kh0, zf, 0, 0, 0);
      t0 = __builtin_amdgcn_mfma_f32_16x16x32_bf16(qh[rf], kl0, t0, 0, 0, 0);
      t0 = __builtin_amdgcn_mfma_f32_16x16x32_bf16(qh[rf], kh0, t0, 0, 0, 0);
      f32x4 t1 = __builtin_amdgcn_mfma_f32_16x16x32_bf16(ql[rf], kh1, zf, 0, 0, 0);
      t1 = __builtin_amdgcn_mfma_f32_16x16x32_bf16(qh[rf], kl1, t1, 0, 0, 0);
      t1 = __builtin_amdgcn_mfma_f32_16x16x32_bf16(qh[rf], kh1, t1, 0, 0, 0);
#pragma unroll
      for (int j = 0; j < 4; ++j) {
        const int gg = rf * 16 + rowg * 4 + j;
        float m0 = Mb[(size_t)gg * N_ + n0 + colq];
        float m1 = Mb[(size_t)gg * N_ + n0 + 16 + colq];
        float p0 = __expf(fmaf(t0[j], scale, m0 - mrow[rf][j]));
        float p1 = __expf(fmaf(t1[j], scale, m1 - mrow[rf][j]));
        unsigned int uh, ul;
        asm("v_cvt_pk_bf16_f32 %0, %1, %2" : "=v"(uh) : "v"(p0), "v"(p1));
        float h0f = __uint_as_float(uh << 16);
        float h1f = __uint_as_float(uh & 0xffff0000u);
        float l0 = p0 - h0f, l1 = p1 - h1f;
        asm("v_cvt_pk_bf16_f32 %0, %1, %2" : "=v"(ul) : "v"(l0), "v"(l1));
        Ph[wid][gg][colq]      = (u16)uh;
        Ph[wid][gg][16 + colq] = (u16)(uh >> 16);
        Pl[wid][gg][colq]      = (u16)ul;
        Pl[wid][gg][16 + colq] = (u16)(ul >> 16);
      }
    }
    // P buffer is per-wave: within-wave DS ordering + lgkmcnt drain suffice.
    asm volatile("s_waitcnt lgkmcnt(0)" ::: "memory");

    bf16x8 ph0 = *(const bf16x8*)&Ph[wid][colq][rowg * 8];
    bf16x8 pl0 = *(const bf16x8*)&Pl[wid][colq][rowg * 8];
    bf16x8 ph1 = *(const bf16x8*)&Ph[wid][16 + colq][rowg * 8];
    bf16x8 pl1 = *(const bf16x8*)&Pl[wid][16 + colq][rowg * 8];

    o[0][0] = __builtin_amdgcn_mfma_f32_16x16x32_bf16(pl0, vh0, o[0][0], 0, 0, 0);
    o[0][0] = __builtin_amdgcn_mfma_f32_16x16x32_bf16(ph0, vl0, o[0][0], 0, 0, 0);
    o[0][0] = __builtin_amdgcn_mfma_f32_16x16x32_bf16(ph0, vh0, o[0][0], 0, 0, 0);
    o[0][1] = __builtin_amdgcn_mfma_f32_16x16x32_bf16(pl0, vh1, o[0][1], 0, 0, 0);
    o[0][1] = __builtin_amdgcn_mfma_f32_16x16x32_bf16(ph0, vl1, o[0][1], 0, 0, 0);
    o[0][1] = __builtin_amdgcn_mfma_f32_16x16x32_bf16(ph0, vh1, o[0][1], 0, 0, 0);
    o[1][0] = __builtin_amdgcn_mfma_f32_16x16x32_bf16(pl1, vh0, o[1][0], 0, 0, 0);
    o[1][0] = __builtin_amdgcn_mfma_f32_16x16x32_bf16(ph1, vl0, o[1][0], 0, 0, 0);
    o[1][0] = __builtin_amdgcn_mfma_f32_16x16x32_bf16(ph1, vh0, o[1][0], 0, 0, 0);
    o[1][1] = __builtin_amdgcn_mfma_f32_16x16x32_bf16(pl1, vh1, o[1][1], 0, 0, 0);
    o[1][1] = __builtin_amdgcn_mfma_f32_16x16x32_bf16(ph1, vl1, o[1][1], 0, 0, 0);
    o[1][1] = __builtin_amdgcn_mfma_f32_16x16x32_bf16(ph1, vh1, o[1][1], 0, 0, 0);
    // row sums: P @ ones (hi + lo), accumulated across tiles
    os[0] = __builtin_amdgcn_mfma_f32_16x16x32_bf16(ph0, ones, os[0], 0, 0, 0);
    os[0] = __builtin_amdgcn_mfma_f32_16x16x32_bf16(pl0, ones, os[0], 0, 0, 0);
    os[1] = __builtin_amdgcn_mfma_f32_16x16x32_bf16(ph1, ones, os[1], 0, 0, 0);
    os[1] = __builtin_amdgcn_mfma_f32_16x16x32_bf16(pl1, ones, os[1], 0, 0, 0);
  }

#pragma unroll
  for (int rf = 0; rf < 2; ++rf)
#pragma unroll
    for (int j = 0; j < 4; ++j) {
      const float inv = 1.f / os[rf][j];
      const int gg = rf * 16 + rowg * 4 + j;
      float v0 = o[rf][0][j] * inv;
      float v1 = o[rf][1][j] * inv;
      u16 h0 = f2b(v0), h1 = f2b(v1);
      Qhi[qb + (size_t)gg * D_ + colq]      = h0;   // in-place O
      Qlo[qb + (size_t)gg * D_ + colq]      = f2b(v0 - b2f(h0));
      Qhi[qb + (size_t)gg * D_ + 16 + colq] = h1;
      Qlo[qb + (size_t)gg * D_ + 16 + colq] = f2b(v1 - b2f(h1));
    }
}

// ---------------------------------------------------------------------------
// Stage-2 FUSED v2 (round-9 verbatim): score GEMM + tanh clip + mask + row
// softmax. 64x512 tile / 512 threads (8 waves: 4 row x 2 col); cross-wave
// softmax combine via tiny LDS. grid 256, id = x*32+z so id%8 == z%8.
__global__ __launch_bounds__(512) void s2fused2_kernel(
    const u16* __restrict__ Ahi, const u16* __restrict__ Alo,
    const u16* __restrict__ Bhi, const u16* __restrict__ Blo,
    const float* __restrict__ mask, float* __restrict__ out)
{
  __shared__ __align__(16) u16 AhS[2048], AlS[2048];    // 64 x 32
  __shared__ __align__(16) u16 BhS[16384], BlS[16384];  // 512 x 32
  __shared__ float Mx[4][16][2], Sm[4][16][2];

  const int id   = blockIdx.x;        // x*32 + z
  const int z    = id & 31;
  const int brow = (id >> 5) * 64;
  const int tid  = threadIdx.x;
  const int wid  = tid >> 6;
  const int lane = tid & 63;
  const int colq = lane & 15, rowg = lane >> 4;
  const int roww = wid >> 1, colw = wid & 1;

  const size_t zoff = (size_t)z * 262144;
  const u16* Az_hi = Ahi + zoff;
  const u16* Az_lo = Alo + zoff;
  const u16* Bz_hi = Bhi + zoff;
  const u16* Bz_lo = Blo + zoff;

  f32x4 acc[16] = {};

  const int srow = lane >> 2;        // 0..15
  const int skk  = (lane & 3) * 8;   // 0,8,16,24

  const size_t ga = (size_t)(brow + wid * 16 + srow) * 512 + skk;
  const int aoff = (roww * 16 + colq) * 32 + rowg * 8;

  for (int k0 = 0; k0 < 512; k0 += 32) {
    if (wid < 4) {
      async16(&AhS[wid * 512], Az_hi + ga + k0);
      async16(&AlS[wid * 512], Az_lo + ga + k0);
    }
#pragma unroll
    for (int c = 0; c < 4; ++c) {
      const int chunk = wid * 4 + c;
      const size_t gb = (size_t)(chunk * 16 + srow) * 512 + skk + k0;
      async16(&BhS[chunk * 512], Bz_hi + gb);
      async16(&BlS[chunk * 512], Bz_lo + gb);
    }
    __syncthreads();

    bf16x8 ah = *(const bf16x8*)&AhS[aoff];
    bf16x8 al = *(const bf16x8*)&AlS[aoff];
#pragma unroll
    for (int nf = 0; nf < 16; ++nf) {
      const int boff = (colw * 256 + nf * 16 + colq) * 32 + rowg * 8;
      bf16x8 bh = *(const bf16x8*)&BhS[boff];
      bf16x8 bl = *(const bf16x8*)&BlS[boff];
      f32x4 t = acc[nf];
      t = __builtin_amdgcn_mfma_f32_16x16x32_bf16(al, bh, t, 0, 0, 0);
      t = __builtin_amdgcn_mfma_f32_16x16x32_bf16(ah, bl, t, 0, 0, 0);
      t = __builtin_amdgcn_mfma_f32_16x16x32_bf16(ah, bh, t, 0, 0, 0);
      acc[nf] = t;
    }
    __syncthreads();
  }

  // epilogue: tanh-clip + mask, then row softmax with 2-wave col combine.
  const float iscale = 0.04419417382415922f;  // 1/sqrt(512)
  const size_t rbase =
      ((size_t)z * 512 + brow + roww * 16 + rowg * 4) * 512 + colw * 256 + colq;

#pragma unroll
  for (int j = 0; j < 4; ++j) {
    const size_t roff = rbase + (size_t)j * 512;
#pragma unroll
    for (int nf = 0; nf < 16; ++nf) {
      float x  = acc[nf][j] * iscale;
      float e2 = __expf(2.f * x);
      float t  = 1.f - 2.f / (e2 + 1.f);
      acc[nf][j] = 10.f * t + mask[roff + nf * 16];
    }
  }
  float mx4[4];
#pragma unroll
  for (int j = 0; j < 4; ++j) {
    float mx = acc[0][j];
#pragma unroll
    for (int nf = 1; nf < 16; ++nf) mx = fmaxf(mx, acc[nf][j]);
#pragma unroll
    for (int w = 1; w < 16; w <<= 1) mx = fmaxf(mx, __shfl_xor(mx, w));
    mx4[j] = mx;
  }
  if (colq == 0) {
#pragma unroll
    for (int j = 0; j < 4; ++j) Mx[roww][rowg * 4 + j][colw] = mx4[j];
  }
  __syncthreads();
  float sm4[4];
#pragma unroll
  for (int j = 0; j < 4; ++j) {
    const float gmx = fmaxf(Mx[roww][rowg * 4 + j][0], Mx[roww][rowg * 4 + j][1]);
    float sum = 0.f;
#pragma unroll
    for (int nf = 0; nf < 16; ++nf) {
      float e = __expf(acc[nf][j] - gmx);
      acc[nf][j] = e;
      sum += e;
    }
#pragma unroll
    for (int w = 1; w < 16; w <<= 1) sum += __shfl_xor(sum, w);
    sm4[j] = sum;
  }
  if (colq == 0) {
#pragma unroll
    for (int j = 0; j < 4; ++j) Sm[roww][rowg * 4 + j][colw] = sm4[j];
  }
  __syncthreads();
#pragma unroll
  for (int j = 0; j < 4; ++j) {
    const float inv = 1.f / (Sm[roww][rowg * 4 + j][0] + Sm[roww][rowg * 4 + j][1]);
    const size_t roff = rbase + (size_t)j * 512;
#pragma unroll
    for (int nf = 0; nf < 16; ++nf)
      out[roff + nf * 16] = acc[nf][j] * inv;
  }
}

// ---------------------------------------------------------------------------
extern "C" void kernel_launch(void* const* d_in, const int* in_sizes, int n_in,
                              void* d_out, int out_size, void* d_ws, size_t ws_size,
                              hipStream_t stream)
{
  const float* enc_nodes = (const float*)d_in[0];
  const float* enc_last  = (const float*)d_in[1];
  const float* mask      = (const float*)d_in[2];
  const float* Wq_graph  = (const float*)d_in[3];
  const float* Wq_first  = (const float*)d_in[4];
  const float* Wq_last   = (const float*)d_in[5];
  const float* Wk        = (const float*)d_in[6];
  const float* Wv        = (const float*)d_in[7];
  const float* Wcomb     = (const float*)d_in[8];
  const float* bcomb     = (const float*)d_in[9];
  float* out = (float*)d_out;

  char* ws = (char*)d_ws;
  size_t off = 0;
  auto alloc = [&](size_t bytes) {
    void* p = ws + off;
    off += (bytes + 255) & ~(size_t)255;
    return p;
  };

  const size_t EL = (size_t)B_ * G_ * D_;  // 8388608
  u16* encNhi = (u16*)alloc(EL * 2);
  u16* encNlo = (u16*)alloc(EL * 2);
  u16* encLhi = (u16*)alloc(EL * 2);   // -> reused as VT hi after q GEMM
  u16* encLlo = (u16*)alloc(EL * 2);   // -> reused as VT lo
  u16* qhi    = (u16*)alloc(EL * 2);   // q -> attn output in-place -> mh GEMM input
  u16* qlo    = (u16*)alloc(EL * 2);
  u16* khi    = (u16*)alloc(EL * 2);   // K [16384][512] -> reused as mh hi
  u16* klo    = (u16*)alloc(EL * 2);   // -> reused as mh lo
  u16* Wqlhi  = (u16*)alloc((size_t)D_ * D_ * 2);
  u16* Wqllo  = (u16*)alloc((size_t)D_ * D_ * 2);
  u16* Wkvhi  = (u16*)alloc((size_t)D_ * D_ * 4);  // [1024][512]
  u16* Wkvlo  = (u16*)alloc((size_t)D_ * D_ * 4);
  u16* Wchi   = (u16*)alloc((size_t)D_ * D_ * 2);
  u16* Wclo   = (u16*)alloc((size_t)D_ * D_ * 2);
  float* partial = (float*)alloc((size_t)B_ * 8 * D_ * 4);
  float* qg      = (float*)alloc((size_t)B_ * D_ * 4);
  float* rowmaxb = (float*)alloc((size_t)B_ * G_ * 4);
  float* kmaxb   = (float*)alloc((size_t)B_ * H_ * 4);
  u16* vThi = encLhi; u16* vTlo = encLlo;  // encL dead after q GEMM
  u16* athi = qhi;    u16* atlo = qlo;     // attention output in-place over q
  u16* mhhi = khi;    u16* mhlo = klo;     // k dead after attention

  mean_split_kernel<<<dim3(32, 8), 512, 0, stream>>>(enc_nodes, encNhi, encNlo, partial);
  meanqg_kernel<<<dim3(32), 512, 0, stream>>>(partial, Wq_graph, qg);
  split4_kernel<<<dim3(8192), 256, 0, stream>>>(enc_last, encLhi, encLlo, (int)(EL / 4));
  wsplit_all_kernel<<<dim3(256, 4), 256, 0, stream>>>(
      Wq_first, Wq_last, Wk, Wv, Wcomb,
      Wqlhi, Wqllo, Wkvhi, Wkvlo, Wchi, Wclo);
  rowmax_kernel<<<dim3(4096), 256, 0, stream>>>(mask, rowmaxb);

  // q = encL @ (Wq_first+Wq_last)^T + qg[b]    (encL dead afterwards)
  gemm_split_kernel<1, 1><<<dim3(512), 256, 0, stream>>>(
      encLhi, encLlo, Wqlhi, Wqllo, qhi, qlo, nullptr, nullptr, qg,
      16384, 512, 512, 128);
  // kv = encN @ [Wk;Wv]^T : K half row-major into khi/klo, V half direct to VT
  gemm_split_kernel<3, 0><<<dim3(1024), 256, 0, stream>>>(
      encNhi, encNlo, Wkvhi, Wkvlo, khi, klo, vThi, vTlo, nullptr,
      16384, 1024, 512, 128);
  // per-(b,h) K norm bound
  kmax_kernel<<<dim3(512), 64, 0, stream>>>(khi, kmaxb);

  attn_mfma6_kernel<<<dim3(2048), 256, 0, stream>>>(
      qhi, qlo, khi, klo, vThi, vTlo, mask, rowmaxb, kmaxb);

  // mh = attn_out @ Wcomb^T + bcomb   (k dead -> mh into k buffers)
  gemm_split_kernel<1, 2><<<dim3(512), 256, 0, stream>>>(
      athi, atlo, Wchi, Wclo, mhhi, mhlo, nullptr, nullptr, bcomb,
      16384, 512, 512, 128);

  // stage-2 fused v2: score GEMM + tanh clip + mask + row softmax -> d_out
  s2fused2_kernel<<<dim3(256), 512, 0, stream>>>(
      mhhi, mhlo, encNhi, encNlo, mask, out);
}

// Round 13
// 471.483 us; speedup vs baseline: 1.0314x; 1.0314x over previous
//
#include <hip/hip_runtime.h>
#include <hip/hip_bf16.h>
#include <stdint.h>
#include <math.h>

// Problem constants
#define B_  32
#define N_  512
#define G_  512
#define D_  512
#define H_  16
#define KD_ 32

using bf16x8 = __attribute__((ext_vector_type(8))) short;
using f32x4  = __attribute__((ext_vector_type(4))) float;
typedef unsigned short u16;

__device__ __forceinline__ u16 f2b(float x) {
  union { __hip_bfloat16 h; u16 u; } c;
  c.h = __float2bfloat16(x);
  return c.u;
}
__device__ __forceinline__ float b2f(u16 u) {
  union { float f; unsigned int i; } c;
  c.i = ((unsigned int)u) << 16;
  return c.f;
}

// async global->LDS, 16B per lane. LDS dest is wave-uniform base; HW adds lane*16.
__device__ __forceinline__ void async16(void* lds, const void* g) {
  __builtin_amdgcn_global_load_lds(
      (const __attribute__((address_space(1))) unsigned int*)(uintptr_t)g,
      (__attribute__((address_space(3))) unsigned int*)(uintptr_t)lds,
      16, 0, 0);
}

// ---------------------------------------------------------------------------
// mean partials fused with hi/lo split of encoded_nodes. grid (32,8), block 512.
__global__ __launch_bounds__(512) void mean_split_kernel(
    const float* __restrict__ enc, u16* __restrict__ hi, u16* __restrict__ lo,
    float* __restrict__ partial)
{
  const int b  = blockIdx.x;
  const int nc = blockIdx.y;       // 8 chunks of 64 n
  const int d  = threadIdx.x;      // 512
  const size_t base = ((size_t)b * N_ + (size_t)nc * 64) * D_ + d;
  float psum = 0.f;
  for (int i = 0; i < 64; ++i) {
    float v = enc[base + (size_t)i * D_];
    psum += v;
    u16 h = f2b(v);
    hi[base + (size_t)i * D_] = h;
    lo[base + (size_t)i * D_] = f2b(v - b2f(h));
  }
  partial[((size_t)b * 8 + nc) * D_ + d] = psum;
}

// graph mean + qg fused: qg[b][d] = dot(mean_n enc[b], Wq_graph[d]). grid 32, block 512.
__global__ __launch_bounds__(512) void meanqg_kernel(
    const float* __restrict__ partial, const float* __restrict__ Wq,
    float* __restrict__ qg)
{
  __shared__ float gl[512];
  const int b = blockIdx.x, d = threadIdx.x;
  float s = 0.f;
  for (int c = 0; c < 8; ++c) s += partial[((size_t)b * 8 + c) * D_ + d];
  gl[d] = s * (1.0f / N_);
  __syncthreads();
  const float* w = Wq + (size_t)d * D_;
  float q = 0.f;
  for (int k = 0; k < D_; ++k) q += gl[k] * w[k];
  qg[b * D_ + d] = q;
}

// generic fp32 -> (hi,lo) bf16 split, 4 elems/thread
__global__ void split4_kernel(const float* __restrict__ in,
                              u16* __restrict__ hi, u16* __restrict__ lo, int n4)
{
  int i = blockIdx.x * blockDim.x + threadIdx.x;
  if (i < n4) {
    float4 v = ((const float4*)in)[i];
    ushort4 h, l;
    h.x = f2b(v.x); l.x = f2b(v.x - b2f(h.x));
    h.y = f2b(v.y); l.y = f2b(v.y - b2f(h.y));
    h.z = f2b(v.z); l.z = f2b(v.z - b2f(h.z));
    h.w = f2b(v.w); l.w = f2b(v.w - b2f(h.w));
    ((ushort4*)hi)[i] = h;
    ((ushort4*)lo)[i] = l;
  }
}

// all weight splits in one launch. grid (256, 4), block 256.
__global__ __launch_bounds__(256) void wsplit_all_kernel(
    const float* __restrict__ Wqf, const float* __restrict__ Wqla,
    const float* __restrict__ Wk,  const float* __restrict__ Wv,
    const float* __restrict__ Wc,
    u16* __restrict__ Wqlhi, u16* __restrict__ Wqllo,
    u16* __restrict__ Wkvhi, u16* __restrict__ Wkvlo,
    u16* __restrict__ Wchi,  u16* __restrict__ Wclo)
{
  const int i = blockIdx.x * 256 + threadIdx.x;   // float4 index < 65536
  const int which = blockIdx.y;
  float4 v;
  u16 *hi, *lo;
  if (which == 0) {
    float4 a = ((const float4*)Wqf)[i];
    float4 b = ((const float4*)Wqla)[i];
    v = make_float4(a.x + b.x, a.y + b.y, a.z + b.z, a.w + b.w);
    hi = Wqlhi; lo = Wqllo;
  } else if (which == 1) {
    v = ((const float4*)Wk)[i]; hi = Wkvhi; lo = Wkvlo;
  } else if (which == 2) {
    v = ((const float4*)Wv)[i]; hi = Wkvhi + 262144; lo = Wkvlo + 262144;
  } else {
    v = ((const float4*)Wc)[i]; hi = Wchi; lo = Wclo;
  }
  ushort4 h, l;
  h.x = f2b(v.x); l.x = f2b(v.x - b2f(h.x));
  h.y = f2b(v.y); l.y = f2b(v.y - b2f(h.y));
  h.z = f2b(v.z); l.z = f2b(v.z - b2f(h.z));
  h.w = f2b(v.w); l.w = f2b(v.w - b2f(h.w));
  ((ushort4*)hi)[i] = h;
  ((ushort4*)lo)[i] = l;
}

// ---------------------------------------------------------------------------
// rowmax of mask per (b,g) row. grid 4096, block 256 (4 rows/block, 1 wave/row).
__global__ __launch_bounds__(256) void rowmax_kernel(
    const float* __restrict__ mask, float* __restrict__ rmx)
{
  const int row  = blockIdx.x * 4 + (threadIdx.x >> 6);
  const int lane = threadIdx.x & 63;
  const float* r = mask + (size_t)row * N_;
  float4 a  = *(const float4*)&r[lane * 8];
  float4 b4 = *(const float4*)&r[lane * 8 + 4];
  float m = fmaxf(fmaxf(fmaxf(a.x, a.y), fmaxf(a.z, a.w)),
                  fmaxf(fmaxf(b4.x, b4.y), fmaxf(b4.z, b4.w)));
#pragma unroll
  for (int w = 1; w < 64; w <<= 1) m = fmaxf(m, __shfl_xor(m, w));
  if (lane == 0) rmx[row] = m;
}

// max_n ||k_n||_2 per (b,h), from khi [16384][512]. grid 512, block 64 (1 wave).
__global__ __launch_bounds__(64) void kmax_kernel(
    const u16* __restrict__ khi, float* __restrict__ kmx)
{
  const int b = blockIdx.x >> 4, h = blockIdx.x & 15;
  const int lane = threadIdx.x;
  float mx = 0.f;
  for (int i = 0; i < 8; ++i) {
    const int n = i * 64 + lane;
    const unsigned int* p =
        (const unsigned int*)&khi[((size_t)b * 512 + n) * 512 + h * 32];
    float s = 0.f;
#pragma unroll
    for (int w = 0; w < 16; ++w) {
      unsigned int u = p[w];
      float f0 = __uint_as_float(u << 16);
      float f1 = __uint_as_float(u & 0xffff0000u);
      s = fmaf(f0, f0, s);
      s = fmaf(f1, f1, s);
    }
    mx = fmaxf(mx, s);
  }
#pragma unroll
  for (int w = 1; w < 64; w <<= 1) mx = fmaxf(mx, __shfl_xor(mx, w));
  if (lane == 0) kmx[blockIdx.x] = sqrtf(mx) * 1.01f;  // covers dropped lo parts
}

// ---------------------------------------------------------------------------
// C[M,N] = A[M,K] @ B[N,K]^T with split-precision bf16 (hi+lo pairs), fp32 accum.
// acc += Alo*Bhi + Ahi*Blo + Ahi*Bhi   (lo*lo dropped, ~2^-18)
// OUTMODE: 1 = hi/lo bf16 row-major,
//          3 = kv fused: c<512 -> K row-major; c>=512 -> VT[b][h][d][n] scatter
// BIASMODE: 0 none, 1 +bias[(r>>9)*512 + c] (qg broadcast), 2 +bias[c] (bcomb)
// 128x128 tile, BK=32, 4 waves (2x2). 1D grid nb, nb%8==0. Y-MAJOR XCD-chunked
// swizzle: each XCD owns a contiguous by-range across all bx -> each A-panel
// read from HBM by exactly ONE XCD (then L2-reused across bx); B (1-4 MB)
// L2-resident per XCD. (x-major variant measured -9us: A re-read per bx.)
template<int OUTMODE, int BIASMODE>
__global__ __launch_bounds__(256) void gemm_split_kernel(
    const u16* __restrict__ Ahi, const u16* __restrict__ Alo,
    const u16* __restrict__ Bhi, const u16* __restrict__ Blo,
    void* __restrict__ Chi, void* __restrict__ Clo,
    void* __restrict__ Dhi, void* __restrict__ Dlo,
    const float* __restrict__ bias,
    int M, int N, int K, int gx)
{
  __shared__ __align__(16) u16 AhS[4096], AlS[4096], BhS[4096], BlS[4096];

  const int nb8     = gridDim.x >> 3;
  const int logical = (blockIdx.x & 7) * nb8 + (blockIdx.x >> 3);
  const int by = logical / gx;          // y-major: bx fastest within a chunk
  const int bx = logical - by * gx;
  const int brow = by * 128;
  const int bcol = bx * 128;

  const int tid  = threadIdx.x;
  const int wid  = tid >> 6;
  const int lane = tid & 63;
  const int wr = wid >> 1, wc = wid & 1;

  f32x4 acc[4][4] = {};

  const int c0   = wid * 2;
  const int srow = lane >> 2;        // 0..15
  const int skk  = (lane & 3) * 8;   // 0,8,16,24

  const size_t g0 = (size_t)(brow + c0 * 16      + srow) * K + skk;
  const size_t g1 = (size_t)(brow + c0 * 16 + 16 + srow) * K + skk;
  const size_t h0 = (size_t)(bcol + c0 * 16      + srow) * K + skk;
  const size_t h1 = (size_t)(bcol + c0 * 16 + 16 + srow) * K + skk;
  u16* lA0 = &AhS[c0 * 512]; u16* lA1 = &AhS[c0 * 512 + 512];
  u16* la0 = &AlS[c0 * 512]; u16* la1 = &AlS[c0 * 512 + 512];
  u16* lB0 = &BhS[c0 * 512]; u16* lB1 = &BhS[c0 * 512 + 512];
  u16* lb0 = &BlS[c0 * 512]; u16* lb1 = &BlS[c0 * 512 + 512];

  const int aoff = (wr * 64 + (lane & 15)) * 32 + (lane >> 4) * 8;
  const int boff = (wc * 64 + (lane & 15)) * 32 + (lane >> 4) * 8;

  for (int k0 = 0; k0 < K; k0 += 32) {
    async16(lA0, Ahi + g0 + k0);
    async16(lA1, Ahi + g1 + k0);
    async16(la0, Alo + g0 + k0);
    async16(la1, Alo + g1 + k0);
    async16(lB0, Bhi + h0 + k0);
    async16(lB1, Bhi + h1 + k0);
    async16(lb0, Blo + h0 + k0);
    async16(lb1, Blo + h1 + k0);
    __syncthreads();   // drains vmcnt(0) before barrier

    bf16x8 ah[4], al[4], bh[4], bl[4];
#pragma unroll
    for (int m = 0; m < 4; ++m) {
      ah[m] = *(const bf16x8*)&AhS[aoff + m * 512];
      al[m] = *(const bf16x8*)&AlS[aoff + m * 512];
    }
#pragma unroll
    for (int n = 0; n < 4; ++n) {
      bh[n] = *(const bf16x8*)&BhS[boff + n * 512];
      bl[n] = *(const bf16x8*)&BlS[boff + n * 512];
    }
#pragma unroll
    for (int m = 0; m < 4; ++m)
#pragma unroll
      for (int n = 0; n < 4; ++n) {
        f32x4 t = acc[m][n];
        t = __builtin_amdgcn_mfma_f32_16x16x32_bf16(al[m], bh[n], t, 0, 0, 0);
        t = __builtin_amdgcn_mfma_f32_16x16x32_bf16(ah[m], bl[n], t, 0, 0, 0);
        t = __builtin_amdgcn_mfma_f32_16x16x32_bf16(ah[m], bh[n], t, 0, 0, 0);
        acc[m][n] = t;
      }
    __syncthreads();   // protect LDS before next stage overwrites
  }

  // epilogue. C/D layout: col = lane&15, row = (lane>>4)*4 + reg
  const int r0 = brow + wr * 64 + (lane >> 4) * 4;
  const int cbase = bcol + wc * 64 + (lane & 15);
#pragma unroll
  for (int m = 0; m < 4; ++m) {
#pragma unroll
    for (int n = 0; n < 4; ++n) {
      const int c = cbase + n * 16;
#pragma unroll
      for (int j = 0; j < 4; ++j) {
        const int r = r0 + m * 16 + j;
        float v = acc[m][n][j];
        if (BIASMODE == 1) v += bias[(r >> 9) * 512 + c];
        if (BIASMODE == 2) v += bias[c];
        u16 hv = f2b(v);
        u16 lv = f2b(v - b2f(hv));
        if (OUTMODE == 1) {
          ((u16*)Chi)[(size_t)r * N + c] = hv;
          ((u16*)Clo)[(size_t)r * N + c] = lv;
        } else {  // OUTMODE == 3
          if (c < 512) {
            ((u16*)Chi)[(size_t)r * 512 + c] = hv;
            ((u16*)Clo)[(size_t)r * 512 + c] = lv;
          } else {
            const int bb = r >> 9, nn = r & 511, hh = (c >> 5) & 15, dd = c & 31;
            const size_t idx = (((size_t)bb * 16 + hh) * 32 + dd) * 512 + nn;
            ((u16*)Dhi)[idx] = hv;
            ((u16*)Dlo)[idx] = lv;
          }
        }
      }
    }
  }
}

// ---------------------------------------------------------------------------
// Stage-1 attention — round-9 attn_mfma6 VERBATIM (known-good: 162us, absmax
// 1.525879e-05). Single pass with analytic shift m_hat >= row max (exact after
// normalization). P hi/lo via v_cvt_pk_bf16_f32; row sums via P@ones MFMA;
// per-wave P LDS (no barriers); O in-place over Q. grid 2048, block 256.
// DO NOT reschedule this kernel (unroll pragmas / hoisted pointer arrays /
// launch_bounds min-waves): two independent attempts (r7, r11) degraded absmax
// 1.5e-5 -> 6-9e-5.
__global__ __launch_bounds__(256) void attn_mfma6_kernel(
    u16* __restrict__ Qhi, u16* __restrict__ Qlo,               // in: Q, out: O
    const u16* __restrict__ Khi, const u16* __restrict__ Klo,   // [16384][512]
    const u16* __restrict__ VThi, const u16* __restrict__ VTlo, // [b][h][32][512]
    const float* __restrict__ mask,
    const float* __restrict__ rowmaxb,   // [16384]
    const float* __restrict__ kmaxb)     // [512]
{
  __shared__ __align__(16) u16 Ph[4][32][56], Pl[4][32][56];  // 112B row stride

  const int tid = threadIdx.x, wid = tid >> 6, lane = tid & 63;
  const int id   = blockIdx.x;
  const int h    = id & 15;
  const int gblk = (id >> 4) & 3;
  const int b    = id >> 6;
  const int g0   = gblk * 128 + wid * 32;
  const int colq = lane & 15, rowg = lane >> 4;

  const size_t qb = ((size_t)b * G_ + g0) * D_ + h * KD_;
  const size_t kb = ((size_t)b * N_) * D_ + h * KD_;
  const size_t vb = (((size_t)b * H_ + h) * KD_) * (size_t)N_;
  const float* Mb = mask + ((size_t)b * G_ + g0) * N_;

  bf16x8 qh[2], ql[2];
  qh[0] = *(const bf16x8*)&Qhi[qb + (size_t)colq * D_ + rowg * 8];
  ql[0] = *(const bf16x8*)&Qlo[qb + (size_t)colq * D_ + rowg * 8];
  qh[1] = *(const bf16x8*)&Qhi[qb + (size_t)(16 + colq) * D_ + rowg * 8];
  ql[1] = *(const bf16x8*)&Qlo[qb + (size_t)(16 + colq) * D_ + rowg * 8];

  const float scale = 0.17677669529663687f;  // 1/sqrt(32)
  const f32x4 zf = {0.f, 0.f, 0.f, 0.f};
  const bf16x8 ones = {0x3F80, 0x3F80, 0x3F80, 0x3F80, 0x3F80, 0x3F80, 0x3F80, 0x3F80};

  // ---- prologue: per-row shift m_hat (upper bound of row max) ----
  const float km = kmaxb[b * 16 + h];
  float nq2[2];
#pragma unroll
  for (int rf = 0; rf < 2; ++rf) {
    float s = 0.f;
    const unsigned int* qw = (const unsigned int*)&qh[rf];
#pragma unroll
    for (int w = 0; w < 4; ++w) {
      unsigned int u = qw[w];
      float f0 = __uint_as_float(u << 16);
      float f1 = __uint_as_float(u & 0xffff0000u);
      s = fmaf(f0, f0, s);
      s = fmaf(f1, f1, s);
    }
    s += __shfl_xor(s, 16);
    s += __shfl_xor(s, 32);
    nq2[rf] = s;
  }
  float mrow[2][4];
#pragma unroll
  for (int rf = 0; rf < 2; ++rf)
#pragma unroll
    for (int j = 0; j < 4; ++j) {
      const int r16 = rowg * 4 + j;
      float nq = sqrtf(__shfl(nq2[rf], r16)) * 1.01f;
      mrow[rf][j] = scale * nq * km + rowmaxb[(size_t)b * G_ + g0 + rf * 16 + r16];
    }

  // ---- single pass: P = exp(s - m_hat), P.V and P.1 accumulation ----
  f32x4 o[2][2] = {};
  f32x4 os[2] = {};

  for (int n0 = 0; n0 < N_; n0 += 32) {
    bf16x8 kh0 = *(const bf16x8*)&Khi[kb + (size_t)(n0 + colq) * D_ + rowg * 8];
    bf16x8 kl0 = *(const bf16x8*)&Klo[kb + (size_t)(n0 + colq) * D_ + rowg * 8];
    bf16x8 kh1 = *(const bf16x8*)&Khi[kb + (size_t)(n0 + 16 + colq) * D_ + rowg * 8];
    bf16x8 kl1 = *(const bf16x8*)&Klo[kb + (size_t)(n0 + 16 + colq) * D_ + rowg * 8];
    // V loads issued early: latency hides under QK^T + softmax VALU work
    bf16x8 vh0 = *(const bf16x8*)&VThi[vb + (size_t)colq * N_ + n0 + rowg * 8];
    bf16x8 vl0 = *(const bf16x8*)&VTlo[vb + (size_t)colq * N_ + n0 + rowg * 8];
    bf16x8 vh1 = *(const bf16x8*)&VThi[vb + (size_t)(16 + colq) * N_ + n0 + rowg * 8];
    bf16x8 vl1 = *(const bf16x8*)&VTlo[vb + (size_t)(16 + colq) * N_ + n0 + rowg * 8];

#pragma unroll
    for (int rf = 0; rf < 2; ++rf) {
      f32x4 t0 = __builtin_amdgcn_mfma_f32_16x16x32_bf16(ql[rf], kh0, zf, 0, 0, 0);
      t0 = __builtin_amdgcn_mfma_f32_16x16x32_bf16(qh[rf], kl0, t0, 0, 0, 0);
      t0 = __builtin_amdgcn_mfma_f32_16x16x32_bf16(qh[rf], kh0, t0, 0, 0, 0);
      f32x4 t1 = __builtin_amdgcn_mfma_f32_16x16x32_bf16(ql[rf], kh1, zf, 0, 0, 0);
      t1 = __builtin_amdgcn_mfma_f32_16x16x32_bf16(qh[rf], kl1, t1, 0, 0, 0);
      t1 = __builtin_amdgcn_mfma_f32_16x16x32_bf16(qh[rf], kh1, t1, 0, 0, 0);
#pragma unroll
      for (int j = 0; j < 4; ++j) {
        const int gg = rf * 16 + rowg * 4 + j;
        float m0 = Mb[(size_t)gg * N_ + n0 + colq];
        float m1 = Mb[(size_t)gg * N_ + n0 + 16 + colq];
        float p0 = __expf(fmaf(t0[j], scale, m0 - mrow[rf][j]));
        float p1 = __expf(fmaf(t1[j], scale, m1 - mrow[rf][j]));
        unsigned int uh, ul;
        asm("v_cvt_pk_bf16_f32 %0, %1, %2" : "=v"(uh) : "v"(p0), "v"(p1));
        float h0f = __uint_as_float(uh << 16);
        float h1f = __uint_as_float(uh & 0xffff0000u);
        float l0 = p0 - h0f, l1 = p1 - h1f;
        asm("v_cvt_pk_bf16_f32 %0, %1, %2" : "=v"(ul) : "v"(l0), "v"(l1));
        Ph[wid][gg][colq]      = (u16)uh;
        Ph[wid][gg][16 + colq] = (u16)(uh >> 16);
        Pl[wid][gg][colq]      = (u16)ul;
        Pl[wid][gg][16 + colq] = (u16)(ul >> 16);
      }
    }
    // P buffer is per-wave: within-wave DS ordering + lgkmcnt drain suffice.
    asm volatile("s_waitcnt lgkmcnt(0)" ::: "memory");

    bf16x8 ph0 = *(const bf16x8*)&Ph[wid][colq][rowg * 8];
    bf16x8 pl0 = *(const bf16x8*)&Pl[wid][colq][rowg * 8];
    bf16x8 ph1 = *(const bf16x8*)&Ph[wid][16 + colq][rowg * 8];
    bf16x8 pl1 = *(const bf16x8*)&Pl[wid][16 + colq][rowg * 8];

    o[0][0] = __builtin_amdgcn_mfma_f32_16x16x32_bf16(pl0, vh0, o[0][0], 0, 0, 0);
    o[0][0] = __builtin_amdgcn_mfma_f32_16x16x32_bf16(ph0, vl0, o[0][0], 0, 0, 0);
    o[0][0] = __builtin_amdgcn_mfma_f32_16x16x32_bf16(ph0, vh0, o[0][0], 0, 0, 0);
    o[0][1] = __builtin_amdgcn_mfma_f32_16x16x32_bf16(pl0, vh1, o[0][1], 0, 0, 0);
    o[0][1] = __builtin_amdgcn_mfma_f32_16x16x32_bf16(ph0, vl1, o[0][1], 0, 0, 0);
    o[0][1] = __builtin_amdgcn_mfma_f32_16x16x32_bf16(ph0, vh1, o[0][1], 0, 0, 0);
    o[1][0] = __builtin_amdgcn_mfma_f32_16x16x32_bf16(pl1, vh0, o[1][0], 0, 0, 0);
    o[1][0] = __builtin_amdgcn_mfma_f32_16x16x32_bf16(ph1, vl0, o[1][0], 0, 0, 0);
    o[1][0] = __builtin_amdgcn_mfma_f32_16x16x32_bf16(ph1, vh0, o[1][0], 0, 0, 0);
    o[1][1] = __builtin_amdgcn_mfma_f32_16x16x32_bf16(pl1, vh1, o[1][1], 0, 0, 0);
    o[1][1] = __builtin_amdgcn_mfma_f32_16x16x32_bf16(ph1, vl1, o[1][1], 0, 0, 0);
    o[1][1] = __builtin_amdgcn_mfma_f32_16x16x32_bf16(ph1, vh1, o[1][1], 0, 0, 0);
    // row sums: P @ ones (hi + lo), accumulated across tiles
    os[0] = __builtin_amdgcn_mfma_f32_16x16x32_bf16(ph0, ones, os[0], 0, 0, 0);
    os[0] = __builtin_amdgcn_mfma_f32_16x16x32_bf16(pl0, ones, os[0], 0, 0, 0);
    os[1] = __builtin_amdgcn_mfma_f32_16x16x32_bf16(ph1, ones, os[1], 0, 0, 0);
    os[1] = __builtin_amdgcn_mfma_f32_16x16x32_bf16(pl1, ones, os[1], 0, 0, 0);
  }

#pragma unroll
  for (int rf = 0; rf < 2; ++rf)
#pragma unroll
    for (int j = 0; j < 4; ++j) {
      const float inv = 1.f / os[rf][j];
      const int gg = rf * 16 + rowg * 4 + j;
      float v0 = o[rf][0][j] * inv;
      float v1 = o[rf][1][j] * inv;
      u16 h0 = f2b(v0), h1 = f2b(v1);
      Qhi[qb + (size_t)gg * D_ + colq]      = h0;   // in-place O
      Qlo[qb + (size_t)gg * D_ + colq]      = f2b(v0 - b2f(h0));
      Qhi[qb + (size_t)gg * D_ + 16 + colq] = h1;
      Qlo[qb + (size_t)gg * D_ + 16 + colq] = f2b(v1 - b2f(h1));
    }
}

// ---------------------------------------------------------------------------
// Stage-2 FUSED v2 (round-9 verbatim): score GEMM + tanh clip + mask + row
// softmax. 64x512 tile / 512 threads (8 waves: 4 row x 2 col); cross-wave
// softmax combine via tiny LDS. grid 256, id = x*32+z so id%8 == z%8.
__global__ __launch_bounds__(512) void s2fused2_kernel(
    const u16* __restrict__ Ahi, const u16* __restrict__ Alo,
    const u16* __restrict__ Bhi, const u16* __restrict__ Blo,
    const float* __restrict__ mask, float* __restrict__ out)
{
  __shared__ __align__(16) u16 AhS[2048], AlS[2048];    // 64 x 32
  __shared__ __align__(16) u16 BhS[16384], BlS[16384];  // 512 x 32
  __shared__ float Mx[4][16][2], Sm[4][16][2];

  const int id   = blockIdx.x;        // x*32 + z
  const int z    = id & 31;
  const int brow = (id >> 5) * 64;
  const int tid  = threadIdx.x;
  const int wid  = tid >> 6;
  const int lane = tid & 63;
  const int colq = lane & 15, rowg = lane >> 4;
  const int roww = wid >> 1, colw = wid & 1;

  const size_t zoff = (size_t)z * 262144;
  const u16* Az_hi = Ahi + zoff;
  const u16* Az_lo = Alo + zoff;
  const u16* Bz_hi = Bhi + zoff;
  const u16* Bz_lo = Blo + zoff;

  f32x4 acc[16] = {};

  const int srow = lane >> 2;        // 0..15
  const int skk  = (lane & 3) * 8;   // 0,8,16,24

  const size_t ga = (size_t)(brow + wid * 16 + srow) * 512 + skk;
  const int aoff = (roww * 16 + colq) * 32 + rowg * 8;

  for (int k0 = 0; k0 < 512; k0 += 32) {
    if (wid < 4) {
      async16(&AhS[wid * 512], Az_hi + ga + k0);
      async16(&AlS[wid * 512], Az_lo + ga + k0);
    }
#pragma unroll
    for (int c = 0; c < 4; ++c) {
      const int chunk = wid * 4 + c;
      const size_t gb = (size_t)(chunk * 16 + srow) * 512 + skk + k0;
      async16(&BhS[chunk * 512], Bz_hi + gb);
      async16(&BlS[chunk * 512], Bz_lo + gb);
    }
    __syncthreads();

    bf16x8 ah = *(const bf16x8*)&AhS[aoff];
    bf16x8 al = *(const bf16x8*)&AlS[aoff];
#pragma unroll
    for (int nf = 0; nf < 16; ++nf) {
      const int boff = (colw * 256 + nf * 16 + colq) * 32 + rowg * 8;
      bf16x8 bh = *(const bf16x8*)&BhS[boff];
      bf16x8 bl = *(const bf16x8*)&BlS[boff];
      f32x4 t = acc[nf];
      t = __builtin_amdgcn_mfma_f32_16x16x32_bf16(al, bh, t, 0, 0, 0);
      t = __builtin_amdgcn_mfma_f32_16x16x32_bf16(ah, bl, t, 0, 0, 0);
      t = __builtin_amdgcn_mfma_f32_16x16x32_bf16(ah, bh, t, 0, 0, 0);
      acc[nf] = t;
    }
    __syncthreads();
  }

  // epilogue: tanh-clip + mask, then row softmax with 2-wave col combine.
  const float iscale = 0.04419417382415922f;  // 1/sqrt(512)
  const size_t rbase =
      ((size_t)z * 512 + brow + roww * 16 + rowg * 4) * 512 + colw * 256 + colq;

#pragma unroll
  for (int j = 0; j < 4; ++j) {
    const size_t roff = rbase + (size_t)j * 512;
#pragma unroll
    for (int nf = 0; nf < 16; ++nf) {
      float x  = acc[nf][j] * iscale;
      float e2 = __expf(2.f * x);
      float t  = 1.f - 2.f / (e2 + 1.f);
      acc[nf][j] = 10.f * t + mask[roff + nf * 16];
    }
  }
  float mx4[4];
#pragma unroll
  for (int j = 0; j < 4; ++j) {
    float mx = acc[0][j];
#pragma unroll
    for (int nf = 1; nf < 16; ++nf) mx = fmaxf(mx, acc[nf][j]);
#pragma unroll
    for (int w = 1; w < 16; w <<= 1) mx = fmaxf(mx, __shfl_xor(mx, w));
    mx4[j] = mx;
  }
  if (colq == 0) {
#pragma unroll
    for (int j = 0; j < 4; ++j) Mx[roww][rowg * 4 + j][colw] = mx4[j];
  }
  __syncthreads();
  float sm4[4];
#pragma unroll
  for (int j = 0; j < 4; ++j) {
    const float gmx = fmaxf(Mx[roww][rowg * 4 + j][0], Mx[roww][rowg * 4 + j][1]);
    float sum = 0.f;
#pragma unroll
    for (int nf = 0; nf < 16; ++nf) {
      float e = __expf(acc[nf][j] - gmx);
      acc[nf][j] = e;
      sum += e;
    }
#pragma unroll
    for (int w = 1; w < 16; w <<= 1) sum += __shfl_xor(sum, w);
    sm4[j] = sum;
  }
  if (colq == 0) {
#pragma unroll
    for (int j = 0; j < 4; ++j) Sm[roww][rowg * 4 + j][colw] = sm4[j];
  }
  __syncthreads();
#pragma unroll
  for (int j = 0; j < 4; ++j) {
    const float inv = 1.f / (Sm[roww][rowg * 4 + j][0] + Sm[roww][rowg * 4 + j][1]);
    const size_t roff = rbase + (size_t)j * 512;
#pragma unroll
    for (int nf = 0; nf < 16; ++nf)
      out[roff + nf * 16] = acc[nf][j] * inv;
  }
}

// ---------------------------------------------------------------------------
extern "C" void kernel_launch(void* const* d_in, const int* in_sizes, int n_in,
                              void* d_out, int out_size, void* d_ws, size_t ws_size,
                              hipStream_t stream)
{
  const float* enc_nodes = (const float*)d_in[0];
  const float* enc_last  = (const float*)d_in[1];
  const float* mask      = (const float*)d_in[2];
  const float* Wq_graph  = (const float*)d_in[3];
  const float* Wq_first  = (const float*)d_in[4];
  const float* Wq_last   = (const float*)d_in[5];
  const float* Wk        = (const float*)d_in[6];
  const float* Wv        = (const float*)d_in[7];
  const float* Wcomb     = (const float*)d_in[8];
  const float* bcomb     = (const float*)d_in[9];
  float* out = (float*)d_out;

  char* ws = (char*)d_ws;
  size_t off = 0;
  auto alloc = [&](size_t bytes) {
    void* p = ws + off;
    off += (bytes + 255) & ~(size_t)255;
    return p;
  };

  const size_t EL = (size_t)B_ * G_ * D_;  // 8388608
  u16* encNhi = (u16*)alloc(EL * 2);
  u16* encNlo = (u16*)alloc(EL * 2);
  u16* encLhi = (u16*)alloc(EL * 2);   // -> reused as VT hi after q GEMM
  u16* encLlo = (u16*)alloc(EL * 2);   // -> reused as VT lo
  u16* qhi    = (u16*)alloc(EL * 2);   // q -> attn output in-place -> mh GEMM input
  u16* qlo    = (u16*)alloc(EL * 2);
  u16* khi    = (u16*)alloc(EL * 2);   // K [16384][512] -> reused as mh hi
  u16* klo    = (u16*)alloc(EL * 2);   // -> reused as mh lo
  u16* Wqlhi  = (u16*)alloc((size_t)D_ * D_ * 2);
  u16* Wqllo  = (u16*)alloc((size_t)D_ * D_ * 2);
  u16* Wkvhi  = (u16*)alloc((size_t)D_ * D_ * 4);  // [1024][512]
  u16* Wkvlo  = (u16*)alloc((size_t)D_ * D_ * 4);
  u16* Wchi   = (u16*)alloc((size_t)D_ * D_ * 2);
  u16* Wclo   = (u16*)alloc((size_t)D_ * D_ * 2);
  float* partial = (float*)alloc((size_t)B_ * 8 * D_ * 4);
  float* qg      = (float*)alloc((size_t)B_ * D_ * 4);
  float* rowmaxb = (float*)alloc((size_t)B_ * G_ * 4);
  float* kmaxb   = (float*)alloc((size_t)B_ * H_ * 4);
  u16* vThi = encLhi; u16* vTlo = encLlo;  // encL dead after q GEMM
  u16* athi = qhi;    u16* atlo = qlo;     // attention output in-place over q
  u16* mhhi = khi;    u16* mhlo = klo;     // k dead after attention

  mean_split_kernel<<<dim3(32, 8), 512, 0, stream>>>(enc_nodes, encNhi, encNlo, partial);
  meanqg_kernel<<<dim3(32), 512, 0, stream>>>(partial, Wq_graph, qg);
  split4_kernel<<<dim3(8192), 256, 0, stream>>>(enc_last, encLhi, encLlo, (int)(EL / 4));
  wsplit_all_kernel<<<dim3(256, 4), 256, 0, stream>>>(
      Wq_first, Wq_last, Wk, Wv, Wcomb,
      Wqlhi, Wqllo, Wkvhi, Wkvlo, Wchi, Wclo);
  rowmax_kernel<<<dim3(4096), 256, 0, stream>>>(mask, rowmaxb);

  // q = encL @ (Wq_first+Wq_last)^T + qg[b]    (encL dead afterwards)
  gemm_split_kernel<1, 1><<<dim3(512), 256, 0, stream>>>(
      encLhi, encLlo, Wqlhi, Wqllo, qhi, qlo, nullptr, nullptr, qg,
      16384, 512, 512, 4);
  // kv = encN @ [Wk;Wv]^T : K half row-major into khi/klo, V half direct to VT
  gemm_split_kernel<3, 0><<<dim3(1024), 256, 0, stream>>>(
      encNhi, encNlo, Wkvhi, Wkvlo, khi, klo, vThi, vTlo, nullptr,
      16384, 1024, 512, 8);
  // per-(b,h) K norm bound
  kmax_kernel<<<dim3(512), 64, 0, stream>>>(khi, kmaxb);

  attn_mfma6_kernel<<<dim3(2048), 256, 0, stream>>>(
      qhi, qlo, khi, klo, vThi, vTlo, mask, rowmaxb, kmaxb);

  // mh = attn_out @ Wcomb^T + bcomb   (k dead -> mh into k buffers)
  gemm_split_kernel<1, 2><<<dim3(512), 256, 0, stream>>>(
      athi, atlo, Wchi, Wclo, mhhi, mhlo, nullptr, nullptr, bcomb,
      16384, 512, 512, 4);

  // stage-2 fused v2: score GEMM + tanh clip + mask + row softmax -> d_out
  s2fused2_kernel<<<dim3(256), 512, 0, stream>>>(
      mhhi, mhlo, encNhi, encNlo, mask, out);
}

// Round 14
// 415.996 us; speedup vs baseline: 1.1689x; 1.1334x over previous
//
#include <hip/hip_runtime.h>
#include <hip/hip_bf16.h>
#include <stdint.h>
#include <math.h>

// Problem constants
#define B_  32
#define N_  512
#define G_  512
#define D_  512
#define H_  16
#define KD_ 32

using bf16x8 = __attribute__((ext_vector_type(8))) short;
using f32x4  = __attribute__((ext_vector_type(4))) float;
typedef unsigned short u16;

__device__ __forceinline__ u16 f2b(float x) {
  union { __hip_bfloat16 h; u16 u; } c;
  c.h = __float2bfloat16(x);
  return c.u;
}
__device__ __forceinline__ float b2f(u16 u) {
  union { float f; unsigned int i; } c;
  c.i = ((unsigned int)u) << 16;
  return c.f;
}

// async global->LDS, 16B per lane. LDS dest is wave-uniform base; HW adds lane*16.
__device__ __forceinline__ void async16(void* lds, const void* g) {
  __builtin_amdgcn_global_load_lds(
      (const __attribute__((address_space(1))) unsigned int*)(uintptr_t)g,
      (__attribute__((address_space(3))) unsigned int*)(uintptr_t)lds,
      16, 0, 0);
}

// ---------------------------------------------------------------------------
// mean partials fused with hi/lo split of encoded_nodes. grid (32,8), block 512.
__global__ __launch_bounds__(512) void mean_split_kernel(
    const float* __restrict__ enc, u16* __restrict__ hi, u16* __restrict__ lo,
    float* __restrict__ partial)
{
  const int b  = blockIdx.x;
  const int nc = blockIdx.y;       // 8 chunks of 64 n
  const int d  = threadIdx.x;      // 512
  const size_t base = ((size_t)b * N_ + (size_t)nc * 64) * D_ + d;
  float psum = 0.f;
  for (int i = 0; i < 64; ++i) {
    float v = enc[base + (size_t)i * D_];
    psum += v;
    u16 h = f2b(v);
    hi[base + (size_t)i * D_] = h;
    lo[base + (size_t)i * D_] = f2b(v - b2f(h));
  }
  partial[((size_t)b * 8 + nc) * D_ + d] = psum;
}

// graph mean + qg fused: qg[b][d] = dot(mean_n enc[b], Wq_graph[d]). grid 32, block 512.
__global__ __launch_bounds__(512) void meanqg_kernel(
    const float* __restrict__ partial, const float* __restrict__ Wq,
    float* __restrict__ qg)
{
  __shared__ float gl[512];
  const int b = blockIdx.x, d = threadIdx.x;
  float s = 0.f;
  for (int c = 0; c < 8; ++c) s += partial[((size_t)b * 8 + c) * D_ + d];
  gl[d] = s * (1.0f / N_);
  __syncthreads();
  const float* w = Wq + (size_t)d * D_;
  float q = 0.f;
  for (int k = 0; k < D_; ++k) q += gl[k] * w[k];
  qg[b * D_ + d] = q;
}

// generic fp32 -> (hi,lo) bf16 split, 4 elems/thread
__global__ void split4_kernel(const float* __restrict__ in,
                              u16* __restrict__ hi, u16* __restrict__ lo, int n4)
{
  int i = blockIdx.x * blockDim.x + threadIdx.x;
  if (i < n4) {
    float4 v = ((const float4*)in)[i];
    ushort4 h, l;
    h.x = f2b(v.x); l.x = f2b(v.x - b2f(h.x));
    h.y = f2b(v.y); l.y = f2b(v.y - b2f(h.y));
    h.z = f2b(v.z); l.z = f2b(v.z - b2f(h.z));
    h.w = f2b(v.w); l.w = f2b(v.w - b2f(h.w));
    ((ushort4*)hi)[i] = h;
    ((ushort4*)lo)[i] = l;
  }
}

// all weight splits in one launch. grid (256, 4), block 256.
__global__ __launch_bounds__(256) void wsplit_all_kernel(
    const float* __restrict__ Wqf, const float* __restrict__ Wqla,
    const float* __restrict__ Wk,  const float* __restrict__ Wv,
    const float* __restrict__ Wc,
    u16* __restrict__ Wqlhi, u16* __restrict__ Wqllo,
    u16* __restrict__ Wkvhi, u16* __restrict__ Wkvlo,
    u16* __restrict__ Wchi,  u16* __restrict__ Wclo)
{
  const int i = blockIdx.x * 256 + threadIdx.x;   // float4 index < 65536
  const int which = blockIdx.y;
  float4 v;
  u16 *hi, *lo;
  if (which == 0) {
    float4 a = ((const float4*)Wqf)[i];
    float4 b = ((const float4*)Wqla)[i];
    v = make_float4(a.x + b.x, a.y + b.y, a.z + b.z, a.w + b.w);
    hi = Wqlhi; lo = Wqllo;
  } else if (which == 1) {
    v = ((const float4*)Wk)[i]; hi = Wkvhi; lo = Wkvlo;
  } else if (which == 2) {
    v = ((const float4*)Wv)[i]; hi = Wkvhi + 262144; lo = Wkvlo + 262144;
  } else {
    v = ((const float4*)Wc)[i]; hi = Wchi; lo = Wclo;
  }
  ushort4 h, l;
  h.x = f2b(v.x); l.x = f2b(v.x - b2f(h.x));
  h.y = f2b(v.y); l.y = f2b(v.y - b2f(h.y));
  h.z = f2b(v.z); l.z = f2b(v.z - b2f(h.z));
  h.w = f2b(v.w); l.w = f2b(v.w - b2f(h.w));
  ((ushort4*)hi)[i] = h;
  ((ushort4*)lo)[i] = l;
}

// ---------------------------------------------------------------------------
// rowmax of mask per (b,g) row. grid 4096, block 256 (4 rows/block, 1 wave/row).
__global__ __launch_bounds__(256) void rowmax_kernel(
    const float* __restrict__ mask, float* __restrict__ rmx)
{
  const int row  = blockIdx.x * 4 + (threadIdx.x >> 6);
  const int lane = threadIdx.x & 63;
  const float* r = mask + (size_t)row * N_;
  float4 a  = *(const float4*)&r[lane * 8];
  float4 b4 = *(const float4*)&r[lane * 8 + 4];
  float m = fmaxf(fmaxf(fmaxf(a.x, a.y), fmaxf(a.z, a.w)),
                  fmaxf(fmaxf(b4.x, b4.y), fmaxf(b4.z, b4.w)));
#pragma unroll
  for (int w = 1; w < 64; w <<= 1) m = fmaxf(m, __shfl_xor(m, w));
  if (lane == 0) rmx[row] = m;
}

// max_n ||k_n||_2 per (b,h), from khi [16384][512]. grid 512, block 64 (1 wave).
__global__ __launch_bounds__(64) void kmax_kernel(
    const u16* __restrict__ khi, float* __restrict__ kmx)
{
  const int b = blockIdx.x >> 4, h = blockIdx.x & 15;
  const int lane = threadIdx.x;
  float mx = 0.f;
  for (int i = 0; i < 8; ++i) {
    const int n = i * 64 + lane;
    const unsigned int* p =
        (const unsigned int*)&khi[((size_t)b * 512 + n) * 512 + h * 32];
    float s = 0.f;
#pragma unroll
    for (int w = 0; w < 16; ++w) {
      unsigned int u = p[w];
      float f0 = __uint_as_float(u << 16);
      float f1 = __uint_as_float(u & 0xffff0000u);
      s = fmaf(f0, f0, s);
      s = fmaf(f1, f1, s);
    }
    mx = fmaxf(mx, s);
  }
#pragma unroll
  for (int w = 1; w < 64; w <<= 1) mx = fmaxf(mx, __shfl_xor(mx, w));
  if (lane == 0) kmx[blockIdx.x] = sqrtf(mx) * 1.01f;  // covers dropped lo parts
}

// ---------------------------------------------------------------------------
// C[M,N] = A[M,K] @ B[N,K]^T with split-precision bf16 (hi+lo pairs), fp32 accum.
// acc += Alo*Bhi + Ahi*Blo + Ahi*Bhi   (lo*lo dropped, ~2^-18)
// OUTMODE: 1 = hi/lo bf16 row-major,
//          3 = kv fused: c<512 -> K row-major; c>=512 -> VT[b][h][d][n] scatter
//              (VT writes vectorized: 4 consecutive nn per lane -> ushort4)
// BIASMODE: 0 none, 1 +bias[(r>>9)*512 + c] (qg broadcast), 2 +bias[c] (bcomb)
// 128x128 tile, BK=32, 4 waves (2x2). 1D grid nb, nb%8==0. Y-MAJOR XCD-chunked
// swizzle (each XCD owns a contiguous by-range across all bx; A-panel read by
// exactly one XCD; x-major variant measured -9us).
template<int OUTMODE, int BIASMODE>
__global__ __launch_bounds__(256) void gemm_split_kernel(
    const u16* __restrict__ Ahi, const u16* __restrict__ Alo,
    const u16* __restrict__ Bhi, const u16* __restrict__ Blo,
    void* __restrict__ Chi, void* __restrict__ Clo,
    void* __restrict__ Dhi, void* __restrict__ Dlo,
    const float* __restrict__ bias,
    int M, int N, int K, int gx)
{
  __shared__ __align__(16) u16 AhS[4096], AlS[4096], BhS[4096], BlS[4096];

  const int nb8     = gridDim.x >> 3;
  const int logical = (blockIdx.x & 7) * nb8 + (blockIdx.x >> 3);
  const int by = logical / gx;          // y-major: bx fastest within a chunk
  const int bx = logical - by * gx;
  const int brow = by * 128;
  const int bcol = bx * 128;

  const int tid  = threadIdx.x;
  const int wid  = tid >> 6;
  const int lane = tid & 63;
  const int wr = wid >> 1, wc = wid & 1;

  f32x4 acc[4][4] = {};

  const int c0   = wid * 2;
  const int srow = lane >> 2;        // 0..15
  const int skk  = (lane & 3) * 8;   // 0,8,16,24

  const size_t g0 = (size_t)(brow + c0 * 16      + srow) * K + skk;
  const size_t g1 = (size_t)(brow + c0 * 16 + 16 + srow) * K + skk;
  const size_t h0 = (size_t)(bcol + c0 * 16      + srow) * K + skk;
  const size_t h1 = (size_t)(bcol + c0 * 16 + 16 + srow) * K + skk;
  u16* lA0 = &AhS[c0 * 512]; u16* lA1 = &AhS[c0 * 512 + 512];
  u16* la0 = &AlS[c0 * 512]; u16* la1 = &AlS[c0 * 512 + 512];
  u16* lB0 = &BhS[c0 * 512]; u16* lB1 = &BhS[c0 * 512 + 512];
  u16* lb0 = &BlS[c0 * 512]; u16* lb1 = &BlS[c0 * 512 + 512];

  const int aoff = (wr * 64 + (lane & 15)) * 32 + (lane >> 4) * 8;
  const int boff = (wc * 64 + (lane & 15)) * 32 + (lane >> 4) * 8;

  for (int k0 = 0; k0 < K; k0 += 32) {
    async16(lA0, Ahi + g0 + k0);
    async16(lA1, Ahi + g1 + k0);
    async16(la0, Alo + g0 + k0);
    async16(la1, Alo + g1 + k0);
    async16(lB0, Bhi + h0 + k0);
    async16(lB1, Bhi + h1 + k0);
    async16(lb0, Blo + h0 + k0);
    async16(lb1, Blo + h1 + k0);
    __syncthreads();   // drains vmcnt(0) before barrier

    bf16x8 ah[4], al[4], bh[4], bl[4];
#pragma unroll
    for (int m = 0; m < 4; ++m) {
      ah[m] = *(const bf16x8*)&AhS[aoff + m * 512];
      al[m] = *(const bf16x8*)&AlS[aoff + m * 512];
    }
#pragma unroll
    for (int n = 0; n < 4; ++n) {
      bh[n] = *(const bf16x8*)&BhS[boff + n * 512];
      bl[n] = *(const bf16x8*)&BlS[boff + n * 512];
    }
#pragma unroll
    for (int m = 0; m < 4; ++m)
#pragma unroll
      for (int n = 0; n < 4; ++n) {
        f32x4 t = acc[m][n];
        t = __builtin_amdgcn_mfma_f32_16x16x32_bf16(al[m], bh[n], t, 0, 0, 0);
        t = __builtin_amdgcn_mfma_f32_16x16x32_bf16(ah[m], bl[n], t, 0, 0, 0);
        t = __builtin_amdgcn_mfma_f32_16x16x32_bf16(ah[m], bh[n], t, 0, 0, 0);
        acc[m][n] = t;
      }
    __syncthreads();   // protect LDS before next stage overwrites
  }

  // epilogue. C/D layout: col = lane&15, row = (lane>>4)*4 + reg
  const int r0 = brow + wr * 64 + (lane >> 4) * 4;
  const int cbase = bcol + wc * 64 + (lane & 15);
#pragma unroll
  for (int m = 0; m < 4; ++m) {
#pragma unroll
    for (int n = 0; n < 4; ++n) {
      const int c = cbase + n * 16;
      if (OUTMODE == 3 && c >= 512) {
        // VT[b][h][d][n]: the 4 regs map to 4 consecutive nn -> one ushort4.
        const int rb = r0 + m * 16;
        const int bb = rb >> 9, nn = rb & 511, hh = (c >> 5) & 15, dd = c & 31;
        const size_t idx = (((size_t)bb * 16 + hh) * 32 + dd) * 512 + nn;
        ushort4 h4, l4;
        {
          float v = acc[m][n][0]; h4.x = f2b(v); l4.x = f2b(v - b2f(h4.x));
          v = acc[m][n][1];       h4.y = f2b(v); l4.y = f2b(v - b2f(h4.y));
          v = acc[m][n][2];       h4.z = f2b(v); l4.z = f2b(v - b2f(h4.z));
          v = acc[m][n][3];       h4.w = f2b(v); l4.w = f2b(v - b2f(h4.w));
        }
        *(ushort4*)&((u16*)Dhi)[idx] = h4;
        *(ushort4*)&((u16*)Dlo)[idx] = l4;
        continue;
      }
#pragma unroll
      for (int j = 0; j < 4; ++j) {
        const int r = r0 + m * 16 + j;
        float v = acc[m][n][j];
        if (BIASMODE == 1) v += bias[(r >> 9) * 512 + c];
        if (BIASMODE == 2) v += bias[c];
        u16 hv = f2b(v);
        u16 lv = f2b(v - b2f(hv));
        if (OUTMODE == 1) {
          ((u16*)Chi)[(size_t)r * N + c] = hv;
          ((u16*)Clo)[(size_t)r * N + c] = lv;
        } else {  // OUTMODE == 3, c < 512: K row-major
          ((u16*)Chi)[(size_t)r * 512 + c] = hv;
          ((u16*)Clo)[(size_t)r * 512 + c] = lv;
        }
      }
    }
  }
}

// ---------------------------------------------------------------------------
// Stage-1 attention — round-9 attn_mfma6 VERBATIM (known-good: 162us, absmax
// 1.525879e-05). Single pass with analytic shift m_hat >= row max (exact after
// normalization). P hi/lo via v_cvt_pk_bf16_f32; row sums via P@ones MFMA;
// per-wave P LDS (no barriers); O in-place over Q. grid 2048, block 256.
// DO NOT reschedule this kernel (unroll pragmas / hoisted pointer arrays /
// launch_bounds min-waves): two independent attempts (r7, r11) degraded absmax
// 1.5e-5 -> 6-9e-5.
__global__ __launch_bounds__(256) void attn_mfma6_kernel(
    u16* __restrict__ Qhi, u16* __restrict__ Qlo,               // in: Q, out: O
    const u16* __restrict__ Khi, const u16* __restrict__ Klo,   // [16384][512]
    const u16* __restrict__ VThi, const u16* __restrict__ VTlo, // [b][h][32][512]
    const float* __restrict__ mask,
    const float* __restrict__ rowmaxb,   // [16384]
    const float* __restrict__ kmaxb)     // [512]
{
  __shared__ __align__(16) u16 Ph[4][32][56], Pl[4][32][56];  // 112B row stride

  const int tid = threadIdx.x, wid = tid >> 6, lane = tid & 63;
  const int id   = blockIdx.x;
  const int h    = id & 15;
  const int gblk = (id >> 4) & 3;
  const int b    = id >> 6;
  const int g0   = gblk * 128 + wid * 32;
  const int colq = lane & 15, rowg = lane >> 4;

  const size_t qb = ((size_t)b * G_ + g0) * D_ + h * KD_;
  const size_t kb = ((size_t)b * N_) * D_ + h * KD_;
  const size_t vb = (((size_t)b * H_ + h) * KD_) * (size_t)N_;
  const float* Mb = mask + ((size_t)b * G_ + g0) * N_;

  bf16x8 qh[2], ql[2];
  qh[0] = *(const bf16x8*)&Qhi[qb + (size_t)colq * D_ + rowg * 8];
  ql[0] = *(const bf16x8*)&Qlo[qb + (size_t)colq * D_ + rowg * 8];
  qh[1] = *(const bf16x8*)&Qhi[qb + (size_t)(16 + colq) * D_ + rowg * 8];
  ql[1] = *(const bf16x8*)&Qlo[qb + (size_t)(16 + colq) * D_ + rowg * 8];

  const float scale = 0.17677669529663687f;  // 1/sqrt(32)
  const f32x4 zf = {0.f, 0.f, 0.f, 0.f};
  const bf16x8 ones = {0x3F80, 0x3F80, 0x3F80, 0x3F80, 0x3F80, 0x3F80, 0x3F80, 0x3F80};

  // ---- prologue: per-row shift m_hat (upper bound of row max) ----
  const float km = kmaxb[b * 16 + h];
  float nq2[2];
#pragma unroll
  for (int rf = 0; rf < 2; ++rf) {
    float s = 0.f;
    const unsigned int* qw = (const unsigned int*)&qh[rf];
#pragma unroll
    for (int w = 0; w < 4; ++w) {
      unsigned int u = qw[w];
      float f0 = __uint_as_float(u << 16);
      float f1 = __uint_as_float(u & 0xffff0000u);
      s = fmaf(f0, f0, s);
      s = fmaf(f1, f1, s);
    }
    s += __shfl_xor(s, 16);
    s += __shfl_xor(s, 32);
    nq2[rf] = s;
  }
  float mrow[2][4];
#pragma unroll
  for (int rf = 0; rf < 2; ++rf)
#pragma unroll
    for (int j = 0; j < 4; ++j) {
      const int r16 = rowg * 4 + j;
      float nq = sqrtf(__shfl(nq2[rf], r16)) * 1.01f;
      mrow[rf][j] = scale * nq * km + rowmaxb[(size_t)b * G_ + g0 + rf * 16 + r16];
    }

  // ---- single pass: P = exp(s - m_hat), P.V and P.1 accumulation ----
  f32x4 o[2][2] = {};
  f32x4 os[2] = {};

  for (int n0 = 0; n0 < N_; n0 += 32) {
    bf16x8 kh0 = *(const bf16x8*)&Khi[kb + (size_t)(n0 + colq) * D_ + rowg * 8];
    bf16x8 kl0 = *(const bf16x8*)&Klo[kb + (size_t)(n0 + colq) * D_ + rowg * 8];
    bf16x8 kh1 = *(const bf16x8*)&Khi[kb + (size_t)(n0 + 16 + colq) * D_ + rowg * 8];
    bf16x8 kl1 = *(const bf16x8*)&Klo[kb + (size_t)(n0 + 16 + colq) * D_ + rowg * 8];
    // V loads issued early: latency hides under QK^T + softmax VALU work
    bf16x8 vh0 = *(const bf16x8*)&VThi[vb + (size_t)colq * N_ + n0 + rowg * 8];
    bf16x8 vl0 = *(const bf16x8*)&VTlo[vb + (size_t)colq * N_ + n0 + rowg * 8];
    bf16x8 vh1 = *(const bf16x8*)&VThi[vb + (size_t)(16 + colq) * N_ + n0 + rowg * 8];
    bf16x8 vl1 = *(const bf16x8*)&VTlo[vb + (size_t)(16 + colq) * N_ + n0 + rowg * 8];

#pragma unroll
    for (int rf = 0; rf < 2; ++rf) {
      f32x4 t0 = __builtin_amdgcn_mfma_f32_16x16x32_bf16(ql[rf], kh0, zf, 0, 0, 0);
      t0 = __builtin_amdgcn_mfma_f32_16x16x32_bf16(qh[rf], kl0, t0, 0, 0, 0);
      t0 = __builtin_amdgcn_mfma_f32_16x16x32_bf16(qh[rf], kh0, t0, 0, 0, 0);
      f32x4 t1 = __builtin_amdgcn_mfma_f32_16x16x32_bf16(ql[rf], kh1, zf, 0, 0, 0);
      t1 = __builtin_amdgcn_mfma_f32_16x16x32_bf16(qh[rf], kl1, t1, 0, 0, 0);
      t1 = __builtin_amdgcn_mfma_f32_16x16x32_bf16(qh[rf], kh1, t1, 0, 0, 0);
#pragma unroll
      for (int j = 0; j < 4; ++j) {
        const int gg = rf * 16 + rowg * 4 + j;
        float m0 = Mb[(size_t)gg * N_ + n0 + colq];
        float m1 = Mb[(size_t)gg * N_ + n0 + 16 + colq];
        float p0 = __expf(fmaf(t0[j], scale, m0 - mrow[rf][j]));
        float p1 = __expf(fmaf(t1[j], scale, m1 - mrow[rf][j]));
        unsigned int uh, ul;
        asm("v_cvt_pk_bf16_f32 %0, %1, %2" : "=v"(uh) : "v"(p0), "v"(p1));
        float h0f = __uint_as_float(uh << 16);
        float h1f = __uint_as_float(uh & 0xffff0000u);
        float l0 = p0 - h0f, l1 = p1 - h1f;
        asm("v_cvt_pk_bf16_f32 %0, %1, %2" : "=v"(ul) : "v"(l0), "v"(l1));
        Ph[wid][gg][colq]      = (u16)uh;
        Ph[wid][gg][16 + colq] = (u16)(uh >> 16);
        Pl[wid][gg][colq]      = (u16)ul;
        Pl[wid][gg][16 + colq] = (u16)(ul >> 16);
      }
    }
    // P buffer is per-wave: within-wave DS ordering + lgkmcnt drain suffice.
    asm volatile("s_waitcnt lgkmcnt(0)" ::: "memory");

    bf16x8 ph0 = *(const bf16x8*)&Ph[wid][colq][rowg * 8];
    bf16x8 pl0 = *(const bf16x8*)&Pl[wid][colq][rowg * 8];
    bf16x8 ph1 = *(const bf16x8*)&Ph[wid][16 + colq][rowg * 8];
    bf16x8 pl1 = *(const bf16x8*)&Pl[wid][16 + colq][rowg * 8];

    o[0][0] = __builtin_amdgcn_mfma_f32_16x16x32_bf16(pl0, vh0, o[0][0], 0, 0, 0);
    o[0][0] = __builtin_amdgcn_mfma_f32_16x16x32_bf16(ph0, vl0, o[0][0], 0, 0, 0);
    o[0][0] = __builtin_amdgcn_mfma_f32_16x16x32_bf16(ph0, vh0, o[0][0], 0, 0, 0);
    o[0][1] = __builtin_amdgcn_mfma_f32_16x16x32_bf16(pl0, vh1, o[0][1], 0, 0, 0);
    o[0][1] = __builtin_amdgcn_mfma_f32_16x16x32_bf16(ph0, vl1, o[0][1], 0, 0, 0);
    o[0][1] = __builtin_amdgcn_mfma_f32_16x16x32_bf16(ph0, vh1, o[0][1], 0, 0, 0);
    o[1][0] = __builtin_amdgcn_mfma_f32_16x16x32_bf16(pl1, vh0, o[1][0], 0, 0, 0);
    o[1][0] = __builtin_amdgcn_mfma_f32_16x16x32_bf16(ph1, vl0, o[1][0], 0, 0, 0);
    o[1][0] = __builtin_amdgcn_mfma_f32_16x16x32_bf16(ph1, vh0, o[1][0], 0, 0, 0);
    o[1][1] = __builtin_amdgcn_mfma_f32_16x16x32_bf16(pl1, vh1, o[1][1], 0, 0, 0);
    o[1][1] = __builtin_amdgcn_mfma_f32_16x16x32_bf16(ph1, vl1, o[1][1], 0, 0, 0);
    o[1][1] = __builtin_amdgcn_mfma_f32_16x16x32_bf16(ph1, vh1, o[1][1], 0, 0, 0);
    // row sums: P @ ones (hi + lo), accumulated across tiles
    os[0] = __builtin_amdgcn_mfma_f32_16x16x32_bf16(ph0, ones, os[0], 0, 0, 0);
    os[0] = __builtin_amdgcn_mfma_f32_16x16x32_bf16(pl0, ones, os[0], 0, 0, 0);
    os[1] = __builtin_amdgcn_mfma_f32_16x16x32_bf16(ph1, ones, os[1], 0, 0, 0);
    os[1] = __builtin_amdgcn_mfma_f32_16x16x32_bf16(pl1, ones, os[1], 0, 0, 0);
  }

#pragma unroll
  for (int rf = 0; rf < 2; ++rf)
#pragma unroll
    for (int j = 0; j < 4; ++j) {
      const float inv = 1.f / os[rf][j];
      const int gg = rf * 16 + rowg * 4 + j;
      float v0 = o[rf][0][j] * inv;
      float v1 = o[rf][1][j] * inv;
      u16 h0 = f2b(v0), h1 = f2b(v1);
      Qhi[qb + (size_t)gg * D_ + colq]      = h0;   // in-place O
      Qlo[qb + (size_t)gg * D_ + colq]      = f2b(v0 - b2f(h0));
      Qhi[qb + (size_t)gg * D_ + 16 + colq] = h1;
      Qlo[qb + (size_t)gg * D_ + 16 + colq] = f2b(v1 - b2f(h1));
    }
}

// ---------------------------------------------------------------------------
// Stage-2 FUSED v3: 32 rows x 512 cols per block of 512 threads (8 waves:
// 2 row-waves x 4 col-waves, each wave 16 rows x 128 cols). LDS 68KB ->
// 2 blocks/CU (v2's 72KB/64-row was 1 block/CU: barrier stalls fully exposed).
// Cross-wave softmax combine over 4 col-waves via tiny LDS. grid 512,
// id = x*32 + z so id%8 == z%8 (batch z's blocks share an XCD L2).
__global__ __launch_bounds__(512) void s2fused3_kernel(
    const u16* __restrict__ Ahi, const u16* __restrict__ Alo,
    const u16* __restrict__ Bhi, const u16* __restrict__ Blo,
    const float* __restrict__ mask, float* __restrict__ out)
{
  __shared__ __align__(16) u16 AhS[1024], AlS[1024];    // 32 x 32
  __shared__ __align__(16) u16 BhS[16384], BlS[16384];  // 512 x 32
  __shared__ float Mx[2][16][4], Sm[2][16][4];

  const int id   = blockIdx.x;        // x*32 + z
  const int z    = id & 31;
  const int brow = (id >> 5) * 32;
  const int tid  = threadIdx.x;
  const int wid  = tid >> 6;
  const int lane = tid & 63;
  const int colq = lane & 15, rowg = lane >> 4;
  const int roww = wid >> 2, colw = wid & 3;

  const size_t zoff = (size_t)z * 262144;
  const u16* Az_hi = Ahi + zoff;
  const u16* Az_lo = Alo + zoff;
  const u16* Bz_hi = Bhi + zoff;
  const u16* Bz_lo = Blo + zoff;

  f32x4 acc[8] = {};

  const int srow = lane >> 2;        // 0..15
  const int skk  = (lane & 3) * 8;   // 0,8,16,24

  const size_t ga = (size_t)(brow + wid * 16 + srow) * 512 + skk;  // wid<2 only
  const int aoff = (roww * 16 + colq) * 32 + rowg * 8;

  for (int k0 = 0; k0 < 512; k0 += 32) {
    if (wid < 2) {
      async16(&AhS[wid * 512], Az_hi + ga + k0);
      async16(&AlS[wid * 512], Az_lo + ga + k0);
    }
#pragma unroll
    for (int c = 0; c < 4; ++c) {
      const int chunk = wid * 4 + c;
      const size_t gb = (size_t)(chunk * 16 + srow) * 512 + skk + k0;
      async16(&BhS[chunk * 512], Bz_hi + gb);
      async16(&BlS[chunk * 512], Bz_lo + gb);
    }
    __syncthreads();

    bf16x8 ah = *(const bf16x8*)&AhS[aoff];
    bf16x8 al = *(const bf16x8*)&AlS[aoff];
#pragma unroll
    for (int nf = 0; nf < 8; ++nf) {
      const int boff = (colw * 128 + nf * 16 + colq) * 32 + rowg * 8;
      bf16x8 bh = *(const bf16x8*)&BhS[boff];
      bf16x8 bl = *(const bf16x8*)&BlS[boff];
      f32x4 t = acc[nf];
      t = __builtin_amdgcn_mfma_f32_16x16x32_bf16(al, bh, t, 0, 0, 0);
      t = __builtin_amdgcn_mfma_f32_16x16x32_bf16(ah, bl, t, 0, 0, 0);
      t = __builtin_amdgcn_mfma_f32_16x16x32_bf16(ah, bh, t, 0, 0, 0);
      acc[nf] = t;
    }
    __syncthreads();
  }

  // epilogue: tanh-clip + mask, then row softmax with 4-wave col combine.
  const float iscale = 0.04419417382415922f;  // 1/sqrt(512)
  const size_t rbase =
      ((size_t)z * 512 + brow + roww * 16 + rowg * 4) * 512 + colw * 128 + colq;

#pragma unroll
  for (int j = 0; j < 4; ++j) {
    const size_t roff = rbase + (size_t)j * 512;
#pragma unroll
    for (int nf = 0; nf < 8; ++nf) {
      float x  = acc[nf][j] * iscale;
      float e2 = __expf(2.f * x);
      float t  = 1.f - 2.f / (e2 + 1.f);
      acc[nf][j] = 10.f * t + mask[roff + nf * 16];
    }
  }
  float mx4[4];
#pragma unroll
  for (int j = 0; j < 4; ++j) {
    float mx = acc[0][j];
#pragma unroll
    for (int nf = 1; nf < 8; ++nf) mx = fmaxf(mx, acc[nf][j]);
#pragma unroll
    for (int w = 1; w < 16; w <<= 1) mx = fmaxf(mx, __shfl_xor(mx, w));
    mx4[j] = mx;
  }
  if (colq == 0) {
#pragma unroll
    for (int j = 0; j < 4; ++j) Mx[roww][rowg * 4 + j][colw] = mx4[j];
  }
  __syncthreads();
  float sm4[4];
#pragma unroll
  for (int j = 0; j < 4; ++j) {
    const float* mr = Mx[roww][rowg * 4 + j];
    const float gmx = fmaxf(fmaxf(mr[0], mr[1]), fmaxf(mr[2], mr[3]));
    float sum = 0.f;
#pragma unroll
    for (int nf = 0; nf < 8; ++nf) {
      float e = __expf(acc[nf][j] - gmx);
      acc[nf][j] = e;
      sum += e;
    }
#pragma unroll
    for (int w = 1; w < 16; w <<= 1) sum += __shfl_xor(sum, w);
    sm4[j] = sum;
  }
  if (colq == 0) {
#pragma unroll
    for (int j = 0; j < 4; ++j) Sm[roww][rowg * 4 + j][colw] = sm4[j];
  }
  __syncthreads();
#pragma unroll
  for (int j = 0; j < 4; ++j) {
    const float* sr = Sm[roww][rowg * 4 + j];
    const float inv = 1.f / (sr[0] + sr[1] + sr[2] + sr[3]);
    const size_t roff = rbase + (size_t)j * 512;
#pragma unroll
    for (int nf = 0; nf < 8; ++nf)
      out[roff + nf * 16] = acc[nf][j] * inv;
  }
}

// ---------------------------------------------------------------------------
extern "C" void kernel_launch(void* const* d_in, const int* in_sizes, int n_in,
                              void* d_out, int out_size, void* d_ws, size_t ws_size,
                              hipStream_t stream)
{
  const float* enc_nodes = (const float*)d_in[0];
  const float* enc_last  = (const float*)d_in[1];
  const float* mask      = (const float*)d_in[2];
  const float* Wq_graph  = (const float*)d_in[3];
  const float* Wq_first  = (const float*)d_in[4];
  const float* Wq_last   = (const float*)d_in[5];
  const float* Wk        = (const float*)d_in[6];
  const float* Wv        = (const float*)d_in[7];
  const float* Wcomb     = (const float*)d_in[8];
  const float* bcomb     = (const float*)d_in[9];
  float* out = (float*)d_out;

  char* ws = (char*)d_ws;
  size_t off = 0;
  auto alloc = [&](size_t bytes) {
    void* p = ws + off;
    off += (bytes + 255) & ~(size_t)255;
    return p;
  };

  const size_t EL = (size_t)B_ * G_ * D_;  // 8388608
  u16* encNhi = (u16*)alloc(EL * 2);
  u16* encNlo = (u16*)alloc(EL * 2);
  u16* encLhi = (u16*)alloc(EL * 2);   // -> reused as VT hi after q GEMM
  u16* encLlo = (u16*)alloc(EL * 2);   // -> reused as VT lo
  u16* qhi    = (u16*)alloc(EL * 2);   // q -> attn output in-place -> mh GEMM input
  u16* qlo    = (u16*)alloc(EL * 2);
  u16* khi    = (u16*)alloc(EL * 2);   // K [16384][512] -> reused as mh hi
  u16* klo    = (u16*)alloc(EL * 2);   // -> reused as mh lo
  u16* Wqlhi  = (u16*)alloc((size_t)D_ * D_ * 2);
  u16* Wqllo  = (u16*)alloc((size_t)D_ * D_ * 2);
  u16* Wkvhi  = (u16*)alloc((size_t)D_ * D_ * 4);  // [1024][512]
  u16* Wkvlo  = (u16*)alloc((size_t)D_ * D_ * 4);
  u16* Wchi   = (u16*)alloc((size_t)D_ * D_ * 2);
  u16* Wclo   = (u16*)alloc((size_t)D_ * D_ * 2);
  float* partial = (float*)alloc((size_t)B_ * 8 * D_ * 4);
  float* qg      = (float*)alloc((size_t)B_ * D_ * 4);
  float* rowmaxb = (float*)alloc((size_t)B_ * G_ * 4);
  float* kmaxb   = (float*)alloc((size_t)B_ * H_ * 4);
  u16* vThi = encLhi; u16* vTlo = encLlo;  // encL dead after q GEMM
  u16* athi = qhi;    u16* atlo = qlo;     // attention output in-place over q
  u16* mhhi = khi;    u16* mhlo = klo;     // k dead after attention

  mean_split_kernel<<<dim3(32, 8), 512, 0, stream>>>(enc_nodes, encNhi, encNlo, partial);
  meanqg_kernel<<<dim3(32), 512, 0, stream>>>(partial, Wq_graph, qg);
  split4_kernel<<<dim3(8192), 256, 0, stream>>>(enc_last, encLhi, encLlo, (int)(EL / 4));
  wsplit_all_kernel<<<dim3(256, 4), 256, 0, stream>>>(
      Wq_first, Wq_last, Wk, Wv, Wcomb,
      Wqlhi, Wqllo, Wkvhi, Wkvlo, Wchi, Wclo);
  rowmax_kernel<<<dim3(4096), 256, 0, stream>>>(mask, rowmaxb);

  // q = encL @ (Wq_first+Wq_last)^T + qg[b]    (encL dead afterwards)
  gemm_split_kernel<1, 1><<<dim3(512), 256, 0, stream>>>(
      encLhi, encLlo, Wqlhi, Wqllo, qhi, qlo, nullptr, nullptr, qg,
      16384, 512, 512, 4);
  // kv = encN @ [Wk;Wv]^T : K half row-major into khi/klo, V half direct to VT
  gemm_split_kernel<3, 0><<<dim3(1024), 256, 0, stream>>>(
      encNhi, encNlo, Wkvhi, Wkvlo, khi, klo, vThi, vTlo, nullptr,
      16384, 1024, 512, 8);
  // per-(b,h) K norm bound
  kmax_kernel<<<dim3(512), 64, 0, stream>>>(khi, kmaxb);

  attn_mfma6_kernel<<<dim3(2048), 256, 0, stream>>>(
      qhi, qlo, khi, klo, vThi, vTlo, mask, rowmaxb, kmaxb);

  // mh = attn_out @ Wcomb^T + bcomb   (k dead -> mh into k buffers)
  gemm_split_kernel<1, 2><<<dim3(512), 256, 0, stream>>>(
      athi, atlo, Wchi, Wclo, mhhi, mhlo, nullptr, nullptr, bcomb,
      16384, 512, 512, 4);

  // stage-2 fused v3: score GEMM + tanh clip + mask + row softmax -> d_out
  s2fused3_kernel<<<dim3(512), 512, 0, stream>>>(
      mhhi, mhlo, encNhi, encNlo, mask, out);
}

// Round 15
// 414.552 us; speedup vs baseline: 1.1730x; 1.0035x over previous
//
#include <hip/hip_runtime.h>
#include <hip/hip_bf16.h>
#include <stdint.h>
#include <math.h>

// Problem constants
#define B_  32
#define N_  512
#define G_  512
#define D_  512
#define H_  16
#define KD_ 32

using bf16x8 = __attribute__((ext_vector_type(8))) short;
using f32x4  = __attribute__((ext_vector_type(4))) float;
typedef unsigned short u16;

__device__ __forceinline__ u16 f2b(float x) {
  union { __hip_bfloat16 h; u16 u; } c;
  c.h = __float2bfloat16(x);
  return c.u;
}
__device__ __forceinline__ float b2f(u16 u) {
  union { float f; unsigned int i; } c;
  c.i = ((unsigned int)u) << 16;
  return c.f;
}

// async global->LDS, 16B per lane. LDS dest is wave-uniform base; HW adds lane*16.
__device__ __forceinline__ void async16(void* lds, const void* g) {
  __builtin_amdgcn_global_load_lds(
      (const __attribute__((address_space(1))) unsigned int*)(uintptr_t)g,
      (__attribute__((address_space(3))) unsigned int*)(uintptr_t)lds,
      16, 0, 0);
}

// ---------------------------------------------------------------------------
// mean partials fused with hi/lo split of encoded_nodes. grid (32,8), block 512.
__global__ __launch_bounds__(512) void mean_split_kernel(
    const float* __restrict__ enc, u16* __restrict__ hi, u16* __restrict__ lo,
    float* __restrict__ partial)
{
  const int b  = blockIdx.x;
  const int nc = blockIdx.y;       // 8 chunks of 64 n
  const int d  = threadIdx.x;      // 512
  const size_t base = ((size_t)b * N_ + (size_t)nc * 64) * D_ + d;
  float psum = 0.f;
  for (int i = 0; i < 64; ++i) {
    float v = enc[base + (size_t)i * D_];
    psum += v;
    u16 h = f2b(v);
    hi[base + (size_t)i * D_] = h;
    lo[base + (size_t)i * D_] = f2b(v - b2f(h));
  }
  partial[((size_t)b * 8 + nc) * D_ + d] = psum;
}

// graph mean + qg fused: qg[b][d] = dot(mean_n enc[b], Wq_graph[d]). grid 32, block 512.
__global__ __launch_bounds__(512) void meanqg_kernel(
    const float* __restrict__ partial, const float* __restrict__ Wq,
    float* __restrict__ qg)
{
  __shared__ float gl[512];
  const int b = blockIdx.x, d = threadIdx.x;
  float s = 0.f;
  for (int c = 0; c < 8; ++c) s += partial[((size_t)b * 8 + c) * D_ + d];
  gl[d] = s * (1.0f / N_);
  __syncthreads();
  const float* w = Wq + (size_t)d * D_;
  float q = 0.f;
  for (int k = 0; k < D_; ++k) q += gl[k] * w[k];
  qg[b * D_ + d] = q;
}

// generic fp32 -> (hi,lo) bf16 split, 4 elems/thread
__global__ void split4_kernel(const float* __restrict__ in,
                              u16* __restrict__ hi, u16* __restrict__ lo, int n4)
{
  int i = blockIdx.x * blockDim.x + threadIdx.x;
  if (i < n4) {
    float4 v = ((const float4*)in)[i];
    ushort4 h, l;
    h.x = f2b(v.x); l.x = f2b(v.x - b2f(h.x));
    h.y = f2b(v.y); l.y = f2b(v.y - b2f(h.y));
    h.z = f2b(v.z); l.z = f2b(v.z - b2f(h.z));
    h.w = f2b(v.w); l.w = f2b(v.w - b2f(h.w));
    ((ushort4*)hi)[i] = h;
    ((ushort4*)lo)[i] = l;
  }
}

// all weight splits in one launch. grid (256, 4), block 256.
__global__ __launch_bounds__(256) void wsplit_all_kernel(
    const float* __restrict__ Wqf, const float* __restrict__ Wqla,
    const float* __restrict__ Wk,  const float* __restrict__ Wv,
    const float* __restrict__ Wc,
    u16* __restrict__ Wqlhi, u16* __restrict__ Wqllo,
    u16* __restrict__ Wkvhi, u16* __restrict__ Wkvlo,
    u16* __restrict__ Wchi,  u16* __restrict__ Wclo)
{
  const int i = blockIdx.x * 256 + threadIdx.x;   // float4 index < 65536
  const int which = blockIdx.y;
  float4 v;
  u16 *hi, *lo;
  if (which == 0) {
    float4 a = ((const float4*)Wqf)[i];
    float4 b = ((const float4*)Wqla)[i];
    v = make_float4(a.x + b.x, a.y + b.y, a.z + b.z, a.w + b.w);
    hi = Wqlhi; lo = Wqllo;
  } else if (which == 1) {
    v = ((const float4*)Wk)[i]; hi = Wkvhi; lo = Wkvlo;
  } else if (which == 2) {
    v = ((const float4*)Wv)[i]; hi = Wkvhi + 262144; lo = Wkvlo + 262144;
  } else {
    v = ((const float4*)Wc)[i]; hi = Wchi; lo = Wclo;
  }
  ushort4 h, l;
  h.x = f2b(v.x); l.x = f2b(v.x - b2f(h.x));
  h.y = f2b(v.y); l.y = f2b(v.y - b2f(h.y));
  h.z = f2b(v.z); l.z = f2b(v.z - b2f(h.z));
  h.w = f2b(v.w); l.w = f2b(v.w - b2f(h.w));
  ((ushort4*)hi)[i] = h;
  ((ushort4*)lo)[i] = l;
}

// ---------------------------------------------------------------------------
// rowmax of mask per (b,g) row. grid 4096, block 256 (4 rows/block, 1 wave/row).
__global__ __launch_bounds__(256) void rowmax_kernel(
    const float* __restrict__ mask, float* __restrict__ rmx)
{
  const int row  = blockIdx.x * 4 + (threadIdx.x >> 6);
  const int lane = threadIdx.x & 63;
  const float* r = mask + (size_t)row * N_;
  float4 a  = *(const float4*)&r[lane * 8];
  float4 b4 = *(const float4*)&r[lane * 8 + 4];
  float m = fmaxf(fmaxf(fmaxf(a.x, a.y), fmaxf(a.z, a.w)),
                  fmaxf(fmaxf(b4.x, b4.y), fmaxf(b4.z, b4.w)));
#pragma unroll
  for (int w = 1; w < 64; w <<= 1) m = fmaxf(m, __shfl_xor(m, w));
  if (lane == 0) rmx[row] = m;
}

// max_n ||k_n||_2 per (b,h), from khi [16384][512]. grid 512, block 64 (1 wave).
__global__ __launch_bounds__(64) void kmax_kernel(
    const u16* __restrict__ khi, float* __restrict__ kmx)
{
  const int b = blockIdx.x >> 4, h = blockIdx.x & 15;
  const int lane = threadIdx.x;
  float mx = 0.f;
  for (int i = 0; i < 8; ++i) {
    const int n = i * 64 + lane;
    const unsigned int* p =
        (const unsigned int*)&khi[((size_t)b * 512 + n) * 512 + h * 32];
    float s = 0.f;
#pragma unroll
    for (int w = 0; w < 16; ++w) {
      unsigned int u = p[w];
      float f0 = __uint_as_float(u << 16);
      float f1 = __uint_as_float(u & 0xffff0000u);
      s = fmaf(f0, f0, s);
      s = fmaf(f1, f1, s);
    }
    mx = fmaxf(mx, s);
  }
#pragma unroll
  for (int w = 1; w < 64; w <<= 1) mx = fmaxf(mx, __shfl_xor(mx, w));
  if (lane == 0) kmx[blockIdx.x] = sqrtf(mx) * 1.01f;  // covers dropped lo parts
}

// ---------------------------------------------------------------------------
// C[M,N] = A[M,K] @ B[N,K]^T with split-precision bf16 (hi+lo pairs), fp32 accum.
// acc += Alo*Bhi + Ahi*Blo + Ahi*Bhi   (lo*lo dropped, ~2^-18)
// OUTMODE: 1 = hi/lo bf16 row-major,
//          3 = kv fused: c<512 -> K row-major; c>=512 -> VT[b][h][d][n] scatter
//              (VT writes vectorized: 4 consecutive nn per lane -> ushort4)
// BIASMODE: 0 none, 1 +bias[(r>>9)*512 + c] (qg broadcast), 2 +bias[c] (bcomb)
// 128x128 tile, BK=32, 4 waves (2x2). 1D grid nb, nb%8==0. Y-MAJOR XCD-chunked
// swizzle (each XCD owns a contiguous by-range across all bx; A-panel read by
// exactly one XCD; x-major variant measured -9us).
template<int OUTMODE, int BIASMODE>
__global__ __launch_bounds__(256) void gemm_split_kernel(
    const u16* __restrict__ Ahi, const u16* __restrict__ Alo,
    const u16* __restrict__ Bhi, const u16* __restrict__ Blo,
    void* __restrict__ Chi, void* __restrict__ Clo,
    void* __restrict__ Dhi, void* __restrict__ Dlo,
    const float* __restrict__ bias,
    int M, int N, int K, int gx)
{
  __shared__ __align__(16) u16 AhS[4096], AlS[4096], BhS[4096], BlS[4096];

  const int nb8     = gridDim.x >> 3;
  const int logical = (blockIdx.x & 7) * nb8 + (blockIdx.x >> 3);
  const int by = logical / gx;          // y-major: bx fastest within a chunk
  const int bx = logical - by * gx;
  const int brow = by * 128;
  const int bcol = bx * 128;

  const int tid  = threadIdx.x;
  const int wid  = tid >> 6;
  const int lane = tid & 63;
  const int wr = wid >> 1, wc = wid & 1;

  f32x4 acc[4][4] = {};

  const int c0   = wid * 2;
  const int srow = lane >> 2;        // 0..15
  const int skk  = (lane & 3) * 8;   // 0,8,16,24

  const size_t g0 = (size_t)(brow + c0 * 16      + srow) * K + skk;
  const size_t g1 = (size_t)(brow + c0 * 16 + 16 + srow) * K + skk;
  const size_t h0 = (size_t)(bcol + c0 * 16      + srow) * K + skk;
  const size_t h1 = (size_t)(bcol + c0 * 16 + 16 + srow) * K + skk;
  u16* lA0 = &AhS[c0 * 512]; u16* lA1 = &AhS[c0 * 512 + 512];
  u16* la0 = &AlS[c0 * 512]; u16* la1 = &AlS[c0 * 512 + 512];
  u16* lB0 = &BhS[c0 * 512]; u16* lB1 = &BhS[c0 * 512 + 512];
  u16* lb0 = &BlS[c0 * 512]; u16* lb1 = &BlS[c0 * 512 + 512];

  const int aoff = (wr * 64 + (lane & 15)) * 32 + (lane >> 4) * 8;
  const int boff = (wc * 64 + (lane & 15)) * 32 + (lane >> 4) * 8;

  for (int k0 = 0; k0 < K; k0 += 32) {
    async16(lA0, Ahi + g0 + k0);
    async16(lA1, Ahi + g1 + k0);
    async16(la0, Alo + g0 + k0);
    async16(la1, Alo + g1 + k0);
    async16(lB0, Bhi + h0 + k0);
    async16(lB1, Bhi + h1 + k0);
    async16(lb0, Blo + h0 + k0);
    async16(lb1, Blo + h1 + k0);
    __syncthreads();   // drains vmcnt(0) before barrier

    bf16x8 ah[4], al[4], bh[4], bl[4];
#pragma unroll
    for (int m = 0; m < 4; ++m) {
      ah[m] = *(const bf16x8*)&AhS[aoff + m * 512];
      al[m] = *(const bf16x8*)&AlS[aoff + m * 512];
    }
#pragma unroll
    for (int n = 0; n < 4; ++n) {
      bh[n] = *(const bf16x8*)&BhS[boff + n * 512];
      bl[n] = *(const bf16x8*)&BlS[boff + n * 512];
    }
#pragma unroll
    for (int m = 0; m < 4; ++m)
#pragma unroll
      for (int n = 0; n < 4; ++n) {
        f32x4 t = acc[m][n];
        t = __builtin_amdgcn_mfma_f32_16x16x32_bf16(al[m], bh[n], t, 0, 0, 0);
        t = __builtin_amdgcn_mfma_f32_16x16x32_bf16(ah[m], bl[n], t, 0, 0, 0);
        t = __builtin_amdgcn_mfma_f32_16x16x32_bf16(ah[m], bh[n], t, 0, 0, 0);
        acc[m][n] = t;
      }
    __syncthreads();   // protect LDS before next stage overwrites
  }

  // epilogue. C/D layout: col = lane&15, row = (lane>>4)*4 + reg
  const int r0 = brow + wr * 64 + (lane >> 4) * 4;
  const int cbase = bcol + wc * 64 + (lane & 15);
#pragma unroll
  for (int m = 0; m < 4; ++m) {
#pragma unroll
    for (int n = 0; n < 4; ++n) {
      const int c = cbase + n * 16;
      if (OUTMODE == 3 && c >= 512) {
        // VT[b][h][d][n]: the 4 regs map to 4 consecutive nn -> one ushort4.
        const int rb = r0 + m * 16;
        const int bb = rb >> 9, nn = rb & 511, hh = (c >> 5) & 15, dd = c & 31;
        const size_t idx = (((size_t)bb * 16 + hh) * 32 + dd) * 512 + nn;
        ushort4 h4, l4;
        {
          float v = acc[m][n][0]; h4.x = f2b(v); l4.x = f2b(v - b2f(h4.x));
          v = acc[m][n][1];       h4.y = f2b(v); l4.y = f2b(v - b2f(h4.y));
          v = acc[m][n][2];       h4.z = f2b(v); l4.z = f2b(v - b2f(h4.z));
          v = acc[m][n][3];       h4.w = f2b(v); l4.w = f2b(v - b2f(h4.w));
        }
        *(ushort4*)&((u16*)Dhi)[idx] = h4;
        *(ushort4*)&((u16*)Dlo)[idx] = l4;
        continue;
      }
#pragma unroll
      for (int j = 0; j < 4; ++j) {
        const int r = r0 + m * 16 + j;
        float v = acc[m][n][j];
        if (BIASMODE == 1) v += bias[(r >> 9) * 512 + c];
        if (BIASMODE == 2) v += bias[c];
        u16 hv = f2b(v);
        u16 lv = f2b(v - b2f(hv));
        if (OUTMODE == 1) {
          ((u16*)Chi)[(size_t)r * N + c] = hv;
          ((u16*)Clo)[(size_t)r * N + c] = lv;
        } else {  // OUTMODE == 3, c < 512: K row-major
          ((u16*)Chi)[(size_t)r * 512 + c] = hv;
          ((u16*)Clo)[(size_t)r * 512 + c] = lv;
        }
      }
    }
  }
}

// ---------------------------------------------------------------------------
// Stage-1 attention v9 = round-9 attn_mfma6 math (per-lane instruction content
// identical) with:
//  * RACE GUARD: sched_barrier(0) after the P-fragment reads. The per-wave
//    P protocol is writes -> lgkm fence -> cross-lane reads; lane-locally the
//    read/write addresses don't overlap, so without this compile-time fence
//    the compiler may hoist NEXT-tile P writes above current-tile P reads
//    (the r7/r11 absmax incidents).
//  * loop-invariant hoisted K/V/mask base pointers (kills per-tile 64-bit
//    address rematerialization; value-neutral).
// No unroll pragma, no launch_bounds min-waves. grid 2048, block 256.
__global__ __launch_bounds__(256) void attn_mfma9_kernel(
    u16* __restrict__ Qhi, u16* __restrict__ Qlo,               // in: Q, out: O
    const u16* __restrict__ Khi, const u16* __restrict__ Klo,   // [16384][512]
    const u16* __restrict__ VThi, const u16* __restrict__ VTlo, // [b][h][32][512]
    const float* __restrict__ mask,
    const float* __restrict__ rowmaxb,   // [16384]
    const float* __restrict__ kmaxb)     // [512]
{
  __shared__ __align__(16) u16 Ph[4][32][56], Pl[4][32][56];  // 112B row stride

  const int tid = threadIdx.x, wid = tid >> 6, lane = tid & 63;
  const int id   = blockIdx.x;
  const int h    = id & 15;
  const int gblk = (id >> 4) & 3;
  const int b    = id >> 6;
  const int g0   = gblk * 128 + wid * 32;
  const int colq = lane & 15, rowg = lane >> 4;

  const size_t qb = ((size_t)b * G_ + g0) * D_ + h * KD_;
  const size_t kb = ((size_t)b * N_) * D_ + h * KD_;
  const size_t vb = (((size_t)b * H_ + h) * KD_) * (size_t)N_;
  const float* Mb = mask + ((size_t)b * G_ + g0) * N_;

  bf16x8 qh[2], ql[2];
  qh[0] = *(const bf16x8*)&Qhi[qb + (size_t)colq * D_ + rowg * 8];
  ql[0] = *(const bf16x8*)&Qlo[qb + (size_t)colq * D_ + rowg * 8];
  qh[1] = *(const bf16x8*)&Qhi[qb + (size_t)(16 + colq) * D_ + rowg * 8];
  ql[1] = *(const bf16x8*)&Qlo[qb + (size_t)(16 + colq) * D_ + rowg * 8];

  const float scale = 0.17677669529663687f;  // 1/sqrt(32)
  const f32x4 zf = {0.f, 0.f, 0.f, 0.f};
  const bf16x8 ones = {0x3F80, 0x3F80, 0x3F80, 0x3F80, 0x3F80, 0x3F80, 0x3F80, 0x3F80};

  // ---- prologue: per-row shift m_hat (upper bound of row max) ----
  const float km = kmaxb[b * 16 + h];
  float nq2[2];
#pragma unroll
  for (int rf = 0; rf < 2; ++rf) {
    float s = 0.f;
    const unsigned int* qw = (const unsigned int*)&qh[rf];
#pragma unroll
    for (int w = 0; w < 4; ++w) {
      unsigned int u = qw[w];
      float f0 = __uint_as_float(u << 16);
      float f1 = __uint_as_float(u & 0xffff0000u);
      s = fmaf(f0, f0, s);
      s = fmaf(f1, f1, s);
    }
    s += __shfl_xor(s, 16);
    s += __shfl_xor(s, 32);
    nq2[rf] = s;
  }
  float mrow[2][4];
#pragma unroll
  for (int rf = 0; rf < 2; ++rf)
#pragma unroll
    for (int j = 0; j < 4; ++j) {
      const int r16 = rowg * 4 + j;
      float nq = sqrtf(__shfl(nq2[rf], r16)) * 1.01f;
      mrow[rf][j] = scale * nq * km + rowmaxb[(size_t)b * G_ + g0 + rf * 16 + r16];
    }

  // hoisted loop-invariant per-lane base pointers
  const u16* Kh0b = Khi  + kb + (size_t)colq * D_ + rowg * 8;
  const u16* Kl0b = Klo  + kb + (size_t)colq * D_ + rowg * 8;
  const u16* Kh1b = Khi  + kb + (size_t)(16 + colq) * D_ + rowg * 8;
  const u16* Kl1b = Klo  + kb + (size_t)(16 + colq) * D_ + rowg * 8;
  const u16* Vh0b = VThi + vb + (size_t)colq * N_ + rowg * 8;
  const u16* Vl0b = VTlo + vb + (size_t)colq * N_ + rowg * 8;
  const u16* Vh1b = VThi + vb + (size_t)(16 + colq) * N_ + rowg * 8;
  const u16* Vl1b = VTlo + vb + (size_t)(16 + colq) * N_ + rowg * 8;
  const float* Mr[2][4];
#pragma unroll
  for (int rf = 0; rf < 2; ++rf)
#pragma unroll
    for (int j = 0; j < 4; ++j)
      Mr[rf][j] = Mb + (size_t)(rf * 16 + rowg * 4 + j) * N_ + colq;

  // ---- single pass: P = exp(s - m_hat), P.V and P.1 accumulation ----
  f32x4 o[2][2] = {};
  f32x4 os[2] = {};

  for (int n0 = 0; n0 < N_; n0 += 32) {
    const size_t ko = (size_t)n0 * D_;
    bf16x8 kh0 = *(const bf16x8*)&Kh0b[ko];
    bf16x8 kl0 = *(const bf16x8*)&Kl0b[ko];
    bf16x8 kh1 = *(const bf16x8*)&Kh1b[ko];
    bf16x8 kl1 = *(const bf16x8*)&Kl1b[ko];
    // V loads issued early: latency hides under QK^T + softmax VALU work
    bf16x8 vh0 = *(const bf16x8*)&Vh0b[n0];
    bf16x8 vl0 = *(const bf16x8*)&Vl0b[n0];
    bf16x8 vh1 = *(const bf16x8*)&Vh1b[n0];
    bf16x8 vl1 = *(const bf16x8*)&Vl1b[n0];

#pragma unroll
    for (int rf = 0; rf < 2; ++rf) {
      f32x4 t0 = __builtin_amdgcn_mfma_f32_16x16x32_bf16(ql[rf], kh0, zf, 0, 0, 0);
      t0 = __builtin_amdgcn_mfma_f32_16x16x32_bf16(qh[rf], kl0, t0, 0, 0, 0);
      t0 = __builtin_amdgcn_mfma_f32_16x16x32_bf16(qh[rf], kh0, t0, 0, 0, 0);
      f32x4 t1 = __builtin_amdgcn_mfma_f32_16x16x32_bf16(ql[rf], kh1, zf, 0, 0, 0);
      t1 = __builtin_amdgcn_mfma_f32_16x16x32_bf16(qh[rf], kl1, t1, 0, 0, 0);
      t1 = __builtin_amdgcn_mfma_f32_16x16x32_bf16(qh[rf], kh1, t1, 0, 0, 0);
#pragma unroll
      for (int j = 0; j < 4; ++j) {
        const int gg = rf * 16 + rowg * 4 + j;
        float m0 = Mr[rf][j][n0];
        float m1 = Mr[rf][j][n0 + 16];
        float p0 = __expf(fmaf(t0[j], scale, m0 - mrow[rf][j]));
        float p1 = __expf(fmaf(t1[j], scale, m1 - mrow[rf][j]));
        unsigned int uh, ul;
        asm("v_cvt_pk_bf16_f32 %0, %1, %2" : "=v"(uh) : "v"(p0), "v"(p1));
        float h0f = __uint_as_float(uh << 16);
        float h1f = __uint_as_float(uh & 0xffff0000u);
        float l0 = p0 - h0f, l1 = p1 - h1f;
        asm("v_cvt_pk_bf16_f32 %0, %1, %2" : "=v"(ul) : "v"(l0), "v"(l1));
        Ph[wid][gg][colq]      = (u16)uh;
        Ph[wid][gg][16 + colq] = (u16)(uh >> 16);
        Pl[wid][gg][colq]      = (u16)ul;
        Pl[wid][gg][16 + colq] = (u16)(ul >> 16);
      }
    }
    // P buffer is per-wave: within-wave DS ordering + lgkmcnt drain suffice.
    asm volatile("s_waitcnt lgkmcnt(0)" ::: "memory");

    bf16x8 ph0 = *(const bf16x8*)&Ph[wid][colq][rowg * 8];
    bf16x8 pl0 = *(const bf16x8*)&Pl[wid][colq][rowg * 8];
    bf16x8 ph1 = *(const bf16x8*)&Ph[wid][16 + colq][rowg * 8];
    bf16x8 pl1 = *(const bf16x8*)&Pl[wid][16 + colq][rowg * 8];
    // RACE GUARD: forbid compiler from hoisting next-tile P writes above
    // these cross-lane reads (lane-local alias analysis can't see the hazard).
    __builtin_amdgcn_sched_barrier(0);

    o[0][0] = __builtin_amdgcn_mfma_f32_16x16x32_bf16(pl0, vh0, o[0][0], 0, 0, 0);
    o[0][0] = __builtin_amdgcn_mfma_f32_16x16x32_bf16(ph0, vl0, o[0][0], 0, 0, 0);
    o[0][0] = __builtin_amdgcn_mfma_f32_16x16x32_bf16(ph0, vh0, o[0][0], 0, 0, 0);
    o[0][1] = __builtin_amdgcn_mfma_f32_16x16x32_bf16(pl0, vh1, o[0][1], 0, 0, 0);
    o[0][1] = __builtin_amdgcn_mfma_f32_16x16x32_bf16(ph0, vl1, o[0][1], 0, 0, 0);
    o[0][1] = __builtin_amdgcn_mfma_f32_16x16x32_bf16(ph0, vh1, o[0][1], 0, 0, 0);
    o[1][0] = __builtin_amdgcn_mfma_f32_16x16x32_bf16(pl1, vh0, o[1][0], 0, 0, 0);
    o[1][0] = __builtin_amdgcn_mfma_f32_16x16x32_bf16(ph1, vl0, o[1][0], 0, 0, 0);
    o[1][0] = __builtin_amdgcn_mfma_f32_16x16x32_bf16(ph1, vh0, o[1][0], 0, 0, 0);
    o[1][1] = __builtin_amdgcn_mfma_f32_16x16x32_bf16(pl1, vh1, o[1][1], 0, 0, 0);
    o[1][1] = __builtin_amdgcn_mfma_f32_16x16x32_bf16(ph1, vl1, o[1][1], 0, 0, 0);
    o[1][1] = __builtin_amdgcn_mfma_f32_16x16x32_bf16(ph1, vh1, o[1][1], 0, 0, 0);
    // row sums: P @ ones (hi + lo), accumulated across tiles
    os[0] = __builtin_amdgcn_mfma_f32_16x16x32_bf16(ph0, ones, os[0], 0, 0, 0);
    os[0] = __builtin_amdgcn_mfma_f32_16x16x32_bf16(pl0, ones, os[0], 0, 0, 0);
    os[1] = __builtin_amdgcn_mfma_f32_16x16x32_bf16(ph1, ones, os[1], 0, 0, 0);
    os[1] = __builtin_amdgcn_mfma_f32_16x16x32_bf16(pl1, ones, os[1], 0, 0, 0);
  }

#pragma unroll
  for (int rf = 0; rf < 2; ++rf)
#pragma unroll
    for (int j = 0; j < 4; ++j) {
      const float inv = 1.f / os[rf][j];
      const int gg = rf * 16 + rowg * 4 + j;
      float v0 = o[rf][0][j] * inv;
      float v1 = o[rf][1][j] * inv;
      u16 h0 = f2b(v0), h1 = f2b(v1);
      Qhi[qb + (size_t)gg * D_ + colq]      = h0;   // in-place O
      Qlo[qb + (size_t)gg * D_ + colq]      = f2b(v0 - b2f(h0));
      Qhi[qb + (size_t)gg * D_ + 16 + colq] = h1;
      Qlo[qb + (size_t)gg * D_ + 16 + colq] = f2b(v1 - b2f(h1));
    }
}

// ---------------------------------------------------------------------------
// Stage-2 FUSED v3 (round-14 verbatim): 32 rows x 512 cols per 512-thread block
// (2 row-waves x 4 col-waves), 68KB LDS -> 2 blocks/CU. grid 512, id = x*32+z.
__global__ __launch_bounds__(512) void s2fused3_kernel(
    const u16* __restrict__ Ahi, const u16* __restrict__ Alo,
    const u16* __restrict__ Bhi, const u16* __restrict__ Blo,
    const float* __restrict__ mask, float* __restrict__ out)
{
  __shared__ __align__(16) u16 AhS[1024], AlS[1024];    // 32 x 32
  __shared__ __align__(16) u16 BhS[16384], BlS[16384];  // 512 x 32
  __shared__ float Mx[2][16][4], Sm[2][16][4];

  const int id   = blockIdx.x;        // x*32 + z
  const int z    = id & 31;
  const int brow = (id >> 5) * 32;
  const int tid  = threadIdx.x;
  const int wid  = tid >> 6;
  const int lane = tid & 63;
  const int colq = lane & 15, rowg = lane >> 4;
  const int roww = wid >> 2, colw = wid & 3;

  const size_t zoff = (size_t)z * 262144;
  const u16* Az_hi = Ahi + zoff;
  const u16* Az_lo = Alo + zoff;
  const u16* Bz_hi = Bhi + zoff;
  const u16* Bz_lo = Blo + zoff;

  f32x4 acc[8] = {};

  const int srow = lane >> 2;        // 0..15
  const int skk  = (lane & 3) * 8;   // 0,8,16,24

  const size_t ga = (size_t)(brow + wid * 16 + srow) * 512 + skk;  // wid<2 only
  const int aoff = (roww * 16 + colq) * 32 + rowg * 8;

  for (int k0 = 0; k0 < 512; k0 += 32) {
    if (wid < 2) {
      async16(&AhS[wid * 512], Az_hi + ga + k0);
      async16(&AlS[wid * 512], Az_lo + ga + k0);
    }
#pragma unroll
    for (int c = 0; c < 4; ++c) {
      const int chunk = wid * 4 + c;
      const size_t gb = (size_t)(chunk * 16 + srow) * 512 + skk + k0;
      async16(&BhS[chunk * 512], Bz_hi + gb);
      async16(&BlS[chunk * 512], Bz_lo + gb);
    }
    __syncthreads();

    bf16x8 ah = *(const bf16x8*)&AhS[aoff];
    bf16x8 al = *(const bf16x8*)&AlS[aoff];
#pragma unroll
    for (int nf = 0; nf < 8; ++nf) {
      const int boff = (colw * 128 + nf * 16 + colq) * 32 + rowg * 8;
      bf16x8 bh = *(const bf16x8*)&BhS[boff];
      bf16x8 bl = *(const bf16x8*)&BlS[boff];
      f32x4 t = acc[nf];
      t = __builtin_amdgcn_mfma_f32_16x16x32_bf16(al, bh, t, 0, 0, 0);
      t = __builtin_amdgcn_mfma_f32_16x16x32_bf16(ah, bl, t, 0, 0, 0);
      t = __builtin_amdgcn_mfma_f32_16x16x32_bf16(ah, bh, t, 0, 0, 0);
      acc[nf] = t;
    }
    __syncthreads();
  }

  // epilogue: tanh-clip + mask, then row softmax with 4-wave col combine.
  const float iscale = 0.04419417382415922f;  // 1/sqrt(512)
  const size_t rbase =
      ((size_t)z * 512 + brow + roww * 16 + rowg * 4) * 512 + colw * 128 + colq;

#pragma unroll
  for (int j = 0; j < 4; ++j) {
    const size_t roff = rbase + (size_t)j * 512;
#pragma unroll
    for (int nf = 0; nf < 8; ++nf) {
      float x  = acc[nf][j] * iscale;
      float e2 = __expf(2.f * x);
      float t  = 1.f - 2.f / (e2 + 1.f);
      acc[nf][j] = 10.f * t + mask[roff + nf * 16];
    }
  }
  float mx4[4];
#pragma unroll
  for (int j = 0; j < 4; ++j) {
    float mx = acc[0][j];
#pragma unroll
    for (int nf = 1; nf < 8; ++nf) mx = fmaxf(mx, acc[nf][j]);
#pragma unroll
    for (int w = 1; w < 16; w <<= 1) mx = fmaxf(mx, __shfl_xor(mx, w));
    mx4[j] = mx;
  }
  if (colq == 0) {
#pragma unroll
    for (int j = 0; j < 4; ++j) Mx[roww][rowg * 4 + j][colw] = mx4[j];
  }
  __syncthreads();
  float sm4[4];
#pragma unroll
  for (int j = 0; j < 4; ++j) {
    const float* mr = Mx[roww][rowg * 4 + j];
    const float gmx = fmaxf(fmaxf(mr[0], mr[1]), fmaxf(mr[2], mr[3]));
    float sum = 0.f;
#pragma unroll
    for (int nf = 0; nf < 8; ++nf) {
      float e = __expf(acc[nf][j] - gmx);
      acc[nf][j] = e;
      sum += e;
    }
#pragma unroll
    for (int w = 1; w < 16; w <<= 1) sum += __shfl_xor(sum, w);
    sm4[j] = sum;
  }
  if (colq == 0) {
#pragma unroll
    for (int j = 0; j < 4; ++j) Sm[roww][rowg * 4 + j][colw] = sm4[j];
  }
  __syncthreads();
#pragma unroll
  for (int j = 0; j < 4; ++j) {
    const float* sr = Sm[roww][rowg * 4 + j];
    const float inv = 1.f / (sr[0] + sr[1] + sr[2] + sr[3]);
    const size_t roff = rbase + (size_t)j * 512;
#pragma unroll
    for (int nf = 0; nf < 8; ++nf)
      out[roff + nf * 16] = acc[nf][j] * inv;
  }
}

// ---------------------------------------------------------------------------
extern "C" void kernel_launch(void* const* d_in, const int* in_sizes, int n_in,
                              void* d_out, int out_size, void* d_ws, size_t ws_size,
                              hipStream_t stream)
{
  const float* enc_nodes = (const float*)d_in[0];
  const float* enc_last  = (const float*)d_in[1];
  const float* mask      = (const float*)d_in[2];
  const float* Wq_graph  = (const float*)d_in[3];
  const float* Wq_first  = (const float*)d_in[4];
  const float* Wq_last   = (const float*)d_in[5];
  const float* Wk        = (const float*)d_in[6];
  const float* Wv        = (const float*)d_in[7];
  const float* Wcomb     = (const float*)d_in[8];
  const float* bcomb     = (const float*)d_in[9];
  float* out = (float*)d_out;

  char* ws = (char*)d_ws;
  size_t off = 0;
  auto alloc = [&](size_t bytes) {
    void* p = ws + off;
    off += (bytes + 255) & ~(size_t)255;
    return p;
  };

  const size_t EL = (size_t)B_ * G_ * D_;  // 8388608
  u16* encNhi = (u16*)alloc(EL * 2);
  u16* encNlo = (u16*)alloc(EL * 2);
  u16* encLhi = (u16*)alloc(EL * 2);   // -> reused as VT hi after q GEMM
  u16* encLlo = (u16*)alloc(EL * 2);   // -> reused as VT lo
  u16* qhi    = (u16*)alloc(EL * 2);   // q -> attn output in-place -> mh GEMM input
  u16* qlo    = (u16*)alloc(EL * 2);
  u16* khi    = (u16*)alloc(EL * 2);   // K [16384][512] -> reused as mh hi
  u16* klo    = (u16*)alloc(EL * 2);   // -> reused as mh lo
  u16* Wqlhi  = (u16*)alloc((size_t)D_ * D_ * 2);
  u16* Wqllo  = (u16*)alloc((size_t)D_ * D_ * 2);
  u16* Wkvhi  = (u16*)alloc((size_t)D_ * D_ * 4);  // [1024][512]
  u16* Wkvlo  = (u16*)alloc((size_t)D_ * D_ * 4);
  u16* Wchi   = (u16*)alloc((size_t)D_ * D_ * 2);
  u16* Wclo   = (u16*)alloc((size_t)D_ * D_ * 2);
  float* partial = (float*)alloc((size_t)B_ * 8 * D_ * 4);
  float* qg      = (float*)alloc((size_t)B_ * D_ * 4);
  float* rowmaxb = (float*)alloc((size_t)B_ * G_ * 4);
  float* kmaxb   = (float*)alloc((size_t)B_ * H_ * 4);
  u16* vThi = encLhi; u16* vTlo = encLlo;  // encL dead after q GEMM
  u16* athi = qhi;    u16* atlo = qlo;     // attention output in-place over q
  u16* mhhi = khi;    u16* mhlo = klo;     // k dead after attention

  mean_split_kernel<<<dim3(32, 8), 512, 0, stream>>>(enc_nodes, encNhi, encNlo, partial);
  meanqg_kernel<<<dim3(32), 512, 0, stream>>>(partial, Wq_graph, qg);
  split4_kernel<<<dim3(8192), 256, 0, stream>>>(enc_last, encLhi, encLlo, (int)(EL / 4));
  wsplit_all_kernel<<<dim3(256, 4), 256, 0, stream>>>(
      Wq_first, Wq_last, Wk, Wv, Wcomb,
      Wqlhi, Wqllo, Wkvhi, Wkvlo, Wchi, Wclo);
  rowmax_kernel<<<dim3(4096), 256, 0, stream>>>(mask, rowmaxb);

  // q = encL @ (Wq_first+Wq_last)^T + qg[b]    (encL dead afterwards)
  gemm_split_kernel<1, 1><<<dim3(512), 256, 0, stream>>>(
      encLhi, encLlo, Wqlhi, Wqllo, qhi, qlo, nullptr, nullptr, qg,
      16384, 512, 512, 4);
  // kv = encN @ [Wk;Wv]^T : K half row-major into khi/klo, V half direct to VT
  gemm_split_kernel<3, 0><<<dim3(1024), 256, 0, stream>>>(
      encNhi, encNlo, Wkvhi, Wkvlo, khi, klo, vThi, vTlo, nullptr,
      16384, 1024, 512, 8);
  // per-(b,h) K norm bound
  kmax_kernel<<<dim3(512), 64, 0, stream>>>(khi, kmaxb);

  attn_mfma9_kernel<<<dim3(2048), 256, 0, stream>>>(
      qhi, qlo, khi, klo, vThi, vTlo, mask, rowmaxb, kmaxb);

  // mh = attn_out @ Wcomb^T + bcomb   (k dead -> mh into k buffers)
  gemm_split_kernel<1, 2><<<dim3(512), 256, 0, stream>>>(
      athi, atlo, Wchi, Wclo, mhhi, mhlo, nullptr, nullptr, bcomb,
      16384, 512, 512, 4);

  // stage-2 fused v3: score GEMM + tanh clip + mask + row softmax -> d_out
  s2fused3_kernel<<<dim3(512), 512, 0, stream>>>(
      mhhi, mhlo, encNhi, encNlo, mask, out);
}